// Round 9
// baseline (535.255 us; speedup 1.0000x reference)
//
#include <hip/hip_runtime.h>
#include <hip/hip_bf16.h>

#define NN 50000          // nodes
#define NE 800000         // edges
#define NR 3              // relations
#define NG 500            // graphs
#define NB (NN * NR)      // (dst, rel) buckets = 150000
#define NCLS 10
#define NCMB 8192         // 8 shapes * 8 colors * 128 positions
#define CHUNK 2048        // scan elements per block
#define NBLK ((NB + CHUNK - 1) / CHUNK)   // 74

typedef __hip_bfloat16 bf16;
typedef __attribute__((ext_vector_type(8))) short short8;   // bf16x8 MFMA frag
typedef __attribute__((ext_vector_type(4))) float floatx4;  // MFMA accumulator

static __device__ __forceinline__ float b2f(bf16 x) { return __bfloat162float(x); }
static __device__ __forceinline__ bf16  f2b(float x) { return __float2bfloat16(x); }
static __device__ __forceinline__ float bs2f(short x) {
    return __bfloat162float(*reinterpret_cast<const bf16*>(&x));
}
static __device__ __forceinline__ short f2bs(float x) {
    bf16 b = __float2bfloat16(x);
    return *reinterpret_cast<const short*>(&b);
}

// ---------------- zero words (graph-capture-safe)
__global__ __launch_bounds__(256) void zero_u32(unsigned* __restrict__ p, long n) {
    long i = (long)blockIdx.x * 256 + threadIdx.x;
    if (i < n) p[i] = 0u;
}

// ---------------- per-(dst,rel) edge counts
__global__ __launch_bounds__(256) void count_edges(const int* __restrict__ ei,
                                                   const int* __restrict__ et,
                                                   int* __restrict__ cnt) {
    int e = blockIdx.x * 256 + threadIdx.x;
    if (e >= NE) return;
    atomicAdd(&cnt[ei[NE + e] * NR + et[e]], 1);
}

// ---------------- counting-sort scan, phase A: per-block (2048-elem) totals
__global__ __launch_bounds__(256) void scan_block_sums(const int* __restrict__ cnt,
                                                       int* __restrict__ bsum) {
    __shared__ int sm[256];
    int b = blockIdx.x, t = threadIdx.x;
    int base = b * CHUNK + t * 8, s = 0;
#pragma unroll
    for (int j = 0; j < 8; ++j) { int i = base + j; if (i < NB) s += cnt[i]; }
    sm[t] = s; __syncthreads();
    for (int st = 128; st; st >>= 1) { if (t < st) sm[t] += sm[t + st]; __syncthreads(); }
    if (!t) bsum[b] = sm[0];
}

// ---------------- phase B: exclusive scan of the 74 block sums
__global__ void scan_base(const int* __restrict__ bsum, int* __restrict__ bbase,
                          int* __restrict__ off) {
    if (threadIdx.x == 0 && blockIdx.x == 0) {
        int run = 0;
        for (int i = 0; i < NBLK; ++i) { bbase[i] = run; run += bsum[i]; }
        off[NB] = run;   // == NE
    }
}

// ---------------- phase C: in-block exclusive scan + base -> off[], cursor[]
__global__ __launch_bounds__(256) void scan_write(const int* __restrict__ cnt,
                                                  const int* __restrict__ bbase,
                                                  int* __restrict__ off,
                                                  int* __restrict__ cursor) {
    int b = blockIdx.x, t = threadIdx.x;
    int base = b * CHUNK + t * 8;
    int v[8], ts = 0;
#pragma unroll
    for (int j = 0; j < 8; ++j) { int i = base + j; v[j] = (i < NB) ? cnt[i] : 0; ts += v[j]; }
    int lane = t & 63, wv = t >> 6;
    int incl = ts;
    for (int d = 1; d < 64; d <<= 1) {
        int o = __shfl_up(incl, d, 64);
        if (lane >= d) incl += o;
    }
    __shared__ int wsum[4];
    if (lane == 63) wsum[wv] = incl;
    __syncthreads();
    int wbase = 0;
    for (int w = 0; w < wv; ++w) wbase += wsum[w];
    int run = bbase[b] + wbase + incl - ts;
#pragma unroll
    for (int j = 0; j < 8; ++j) {
        int i = base + j;
        if (i < NB) { off[i] = run; cursor[i] = run; }
        run += v[j];
    }
}

// ---------------- bucket-sort edge src indices (CSR payload)
__global__ __launch_bounds__(256) void scatter_edges(const int* __restrict__ ei,
                                                     const int* __restrict__ et,
                                                     int* __restrict__ cursor,
                                                     int* __restrict__ eidx) {
    int e = blockIdx.x * 256 + threadIdx.x;
    if (e >= NE) return;
    int b = ei[NE + e] * NR + et[e];
    int pos = atomicAdd(&cursor[b], 1);
    eidx[pos] = ei[e];
}

// ---------------- layer-1 tables: tab[r][row][n], r in 0..3 (3 rels + root)
__global__ __launch_bounds__(256) void tab_gemm(const float* __restrict__ se,
                                                const float* __restrict__ ce,
                                                const float* __restrict__ pe,
                                                const float* __restrict__ W1,
                                                const float* __restrict__ root1,
                                                float* __restrict__ tab) {
    int bid = blockIdx.x;              // 4*144 blocks
    int r = bid / 144, row = bid % 144;
    int t = threadIdx.x;               // output column 0..255
    const float* A; int segk;
    if (row < 8)       { A = se + row * 128;        segk = 0; }
    else if (row < 16) { A = ce + (row - 8) * 128;  segk = 128; }
    else               { A = pe + (row - 16) * 128; segk = 256; }
    const float* W = (r < 3) ? (W1 + (size_t)r * 384 * 256) : root1;
    float acc = 0.f;
    for (int k = 0; k < 128; ++k)
        acc += A[k] * W[(size_t)(segk + k) * 256 + t];
    tab[((size_t)r * 144 + row) * 256 + t] = acc;
}

// ---------------- node combo ids: combo[n] = s*1024 + c*128 + p
__global__ __launch_bounds__(256) void node_combo(const int* __restrict__ s,
                                                  const int* __restrict__ c,
                                                  const int* __restrict__ p,
                                                  int* __restrict__ combo) {
    int n = blockIdx.x * 256 + threadIdx.x;
    if (n < NN) combo[n] = (s[n] << 10) | (c[n] << 7) | p[n];
}

// ---------------- comb[r][cmb][d] = tab[r][s]+tab[r][8+c]+tab[r][16+p] (+b1 for r=3), bf16
__global__ __launch_bounds__(256) void comb_build(const float* __restrict__ tab,
                                                  const float* __restrict__ b1,
                                                  bf16* __restrict__ comb) {
    int bid = blockIdx.x;              // 4*8192
    int r = bid >> 13, cmb = bid & (NCMB - 1);
    int d = threadIdx.x;
    int si = cmb >> 10, ci = (cmb >> 7) & 7, pi = cmb & 127;
    const float* tr = tab + (size_t)r * 144 * 256;
    float v = tr[si * 256 + d] + tr[(8 + ci) * 256 + d] + tr[(16 + pi) * 256 + d];
    if (r == 3) v += b1[d];
    comb[(size_t)bid * 256 + d] = f2b(v);
}

// ---------------- fused layer 1: 4 waves/block, 1 wave/dst.
// Lane-split gather: half = lane>>5 handles alternate rows; 32 lanes x short8 = 512 B row.
// 4x unrolled per half -> 8 independent row loads in flight per wave.
__global__ __launch_bounds__(256) void l1_fused(const int* __restrict__ off,
                                                const int* __restrict__ eidx,
                                                const int* __restrict__ combo,
                                                const bf16* __restrict__ comb,
                                                bf16* __restrict__ h1) {
    int wave = threadIdx.x >> 6, lane = threadIdx.x & 63;
    int dst = blockIdx.x * 4 + wave;
    if (dst >= NN) return;
    int half = lane >> 5, li8 = (lane & 31) * 8;
    float acc[8];
    if (half == 0) {   // root slice (b1 pre-folded); only half0's acc is used
        int cmbD = combo[dst];
        short8 rv = *(const short8*)(comb + ((size_t)(3 * NCMB) + cmbD) * 256 + li8);
#pragma unroll
        for (int i = 0; i < 8; ++i) acc[i] = bs2f(rv[i]);
    } else {
#pragma unroll
        for (int i = 0; i < 8; ++i) acc[i] = 0.f;
    }
    for (int r = 0; r < NR; ++r) {
        int lo = off[dst * NR + r], hi = off[dst * NR + r + 1];
        if (hi <= lo) continue;                 // empty bucket contributes 0 (matches ref)
        const bf16* cr = comb + (size_t)r * NCMB * 256;
        float s[8] = {};
        int j = lo;
        for (; j + 8 <= hi; j += 8) {           // 4 edges/half -> 8 rows in flight
            int e0 = eidx[j + half],     e1 = eidx[j + 2 + half];
            int e2 = eidx[j + 4 + half], e3 = eidx[j + 6 + half];
            int c0 = combo[e0], c1 = combo[e1], c2 = combo[e2], c3 = combo[e3];
            short8 v0 = *(const short8*)(cr + (size_t)c0 * 256 + li8);
            short8 v1 = *(const short8*)(cr + (size_t)c1 * 256 + li8);
            short8 v2 = *(const short8*)(cr + (size_t)c2 * 256 + li8);
            short8 v3 = *(const short8*)(cr + (size_t)c3 * 256 + li8);
#pragma unroll
            for (int i = 0; i < 8; ++i)
                s[i] += (bs2f(v0[i]) + bs2f(v1[i])) + (bs2f(v2[i]) + bs2f(v3[i]));
        }
        for (; j + 2 <= hi; j += 2) {
            int e0 = eidx[j + half];
            short8 v0 = *(const short8*)(cr + (size_t)combo[e0] * 256 + li8);
#pragma unroll
            for (int i = 0; i < 8; ++i) s[i] += bs2f(v0[i]);
        }
        if (j < hi && half == 0) {              // odd remainder
            short8 v0 = *(const short8*)(cr + (size_t)combo[eidx[j]] * 256 + li8);
#pragma unroll
            for (int i = 0; i < 8; ++i) s[i] += bs2f(v0[i]);
        }
        float inv = 1.0f / (float)(hi - lo);
#pragma unroll
        for (int i = 0; i < 8; ++i) {
            float tot = s[i] + __shfl_xor(s[i], 32);
            if (half == 0) acc[i] += tot * inv;
        }
    }
    if (half == 0) {
        short8 o;
#pragma unroll
        for (int i = 0; i < 8; ++i) o[i] = f2bs(fmaxf(acc[i], 0.f));
        *(short8*)(h1 + (size_t)dst * 256 + li8) = o;
    }
}

// ---------------- per-relation mean aggregation of h1 (aggregate BEFORE transform):
// hagg[dst][r*256+d] = mean_{src in bucket(dst,r)} h1[src][d]   (0 if empty)
__global__ __launch_bounds__(256) void agg_all(const int* __restrict__ off,
                                               const int* __restrict__ eidx,
                                               const bf16* __restrict__ h1,
                                               bf16* __restrict__ hagg) {
    int wave = threadIdx.x >> 6, lane = threadIdx.x & 63;
    int dst = blockIdx.x * 4 + wave;
    if (dst >= NN) return;
    int half = lane >> 5, li8 = (lane & 31) * 8;
    for (int r = 0; r < NR; ++r) {
        int lo = off[dst * NR + r], hi = off[dst * NR + r + 1];
        float s[8] = {};
        int j = lo;
        for (; j + 8 <= hi; j += 8) {           // 4 edges/half -> 8 rows in flight
            int e0 = eidx[j + half],     e1 = eidx[j + 2 + half];
            int e2 = eidx[j + 4 + half], e3 = eidx[j + 6 + half];
            short8 v0 = *(const short8*)(h1 + (size_t)e0 * 256 + li8);
            short8 v1 = *(const short8*)(h1 + (size_t)e1 * 256 + li8);
            short8 v2 = *(const short8*)(h1 + (size_t)e2 * 256 + li8);
            short8 v3 = *(const short8*)(h1 + (size_t)e3 * 256 + li8);
#pragma unroll
            for (int i = 0; i < 8; ++i)
                s[i] += (bs2f(v0[i]) + bs2f(v1[i])) + (bs2f(v2[i]) + bs2f(v3[i]));
        }
        for (; j + 2 <= hi; j += 2) {
            int e0 = eidx[j + half];
            short8 v0 = *(const short8*)(h1 + (size_t)e0 * 256 + li8);
#pragma unroll
            for (int i = 0; i < 8; ++i) s[i] += bs2f(v0[i]);
        }
        if (j < hi && half == 0) {
            short8 v0 = *(const short8*)(h1 + (size_t)eidx[j] * 256 + li8);
#pragma unroll
            for (int i = 0; i < 8; ++i) s[i] += bs2f(v0[i]);
        }
        float inv = (hi > lo) ? 1.0f / (float)(hi - lo) : 0.f;
        short8 o;
#pragma unroll
        for (int i = 0; i < 8; ++i) {
            float tot = s[i] + __shfl_xor(s[i], 32);
            o[i] = f2bs(tot * inv);
        }
        if (half == 0)
            *(short8*)(hagg + (size_t)dst * 768 + r * 256 + li8) = o;
    }
}

// ---------------- W2cat -> bf16, transposed on K: Wt[n][k], k = [W2_0;W2_1;W2_2;root2]
__global__ __launch_bounds__(256) void conv_w2cat(const float* __restrict__ W2,
                                                  const float* __restrict__ root2,
                                                  bf16* __restrict__ Wt) {
    int idx = blockIdx.x * 256 + threadIdx.x;   // 256*1024
    if (idx >= 256 * 1024) return;
    int n = idx >> 10, k = idx & 1023;
    float v = (k < 768) ? W2[((size_t)(k >> 8) * 256 + (k & 255)) * 256 + n]
                        : root2[(size_t)(k - 768) * 256 + n];
    Wt[idx] = f2b(v);
}

// ---------------- concat MFMA GEMM, v3: BARRIER-FREE direct-global fragments.
// h2[M][256] = relu( [hagg | h1] (M x 1024) @ Wt^T + b2 )
// Block = 32 rows; wave w owns cols w*64..w*64+64 (2x4 grid of 16x16x32 MFMAs).
// A frags: lane l16 = row, quad = k-offset (native MFMA A layout, b128 global loads).
// B frags: Wt[n][k] row-major-K -> lane l16 = col, quad = k-offset; Wt is 512 KB,
// identical across blocks -> L1/L2-hot broadcast. No LDS, no __syncthreads.
__global__ __launch_bounds__(256) void gemm_cat(const bf16* __restrict__ hagg,
                                                const bf16* __restrict__ h1,
                                                const bf16* __restrict__ Wt,
                                                const float* __restrict__ bias,
                                                bf16* __restrict__ h2) {
    const int t = threadIdx.x;
    const int wave = t >> 6, lane = t & 63;
    const int quad = lane >> 4, l16 = lane & 15;
    const int row0 = blockIdx.x * 32;
    const int col0 = wave * 64;

    floatx4 acc[2][4] = {};

    const bf16* a0 = hagg + (size_t)(row0 + l16) * 768 + quad * 8;        // rows row0+l16, +16
    const bf16* a1 = hagg + (size_t)(row0 + 16 + l16) * 768 + quad * 8;
    const bf16* h0p = h1 + (size_t)(row0 + l16) * 256 + quad * 8;
    const bf16* h1p = h1 + (size_t)(row0 + 16 + l16) * 256 + quad * 8;

#pragma unroll 2
    for (int k0 = 0; k0 < 768; k0 += 32) {
        short8 af0 = *(const short8*)(a0 + k0);
        short8 af1 = *(const short8*)(a1 + k0);
        short8 bfr[4];
#pragma unroll
        for (int ni = 0; ni < 4; ++ni)
            bfr[ni] = *(const short8*)(Wt + (size_t)(col0 + ni * 16 + l16) * 1024 + k0 + quad * 8);
#pragma unroll
        for (int ni = 0; ni < 4; ++ni) {
            acc[0][ni] = __builtin_amdgcn_mfma_f32_16x16x32_bf16(af0, bfr[ni], acc[0][ni], 0, 0, 0);
            acc[1][ni] = __builtin_amdgcn_mfma_f32_16x16x32_bf16(af1, bfr[ni], acc[1][ni], 0, 0, 0);
        }
    }
#pragma unroll 2
    for (int k0 = 0; k0 < 256; k0 += 32) {
        short8 af0 = *(const short8*)(h0p + k0);
        short8 af1 = *(const short8*)(h1p + k0);
        short8 bfr[4];
#pragma unroll
        for (int ni = 0; ni < 4; ++ni)
            bfr[ni] = *(const short8*)(Wt + (size_t)(col0 + ni * 16 + l16) * 1024 + 768 + k0 + quad * 8);
#pragma unroll
        for (int ni = 0; ni < 4; ++ni) {
            acc[0][ni] = __builtin_amdgcn_mfma_f32_16x16x32_bf16(af0, bfr[ni], acc[0][ni], 0, 0, 0);
            acc[1][ni] = __builtin_amdgcn_mfma_f32_16x16x32_bf16(af1, bfr[ni], acc[1][ni], 0, 0, 0);
        }
    }

    // C/D layout: col = lane&15, row = quad*4 + reg   [m89/m91-verified]
#pragma unroll
    for (int mi = 0; mi < 2; ++mi) {
#pragma unroll
        for (int ni = 0; ni < 4; ++ni) {
            int n = col0 + ni * 16 + l16;
            float bn = bias[n];
#pragma unroll
            for (int ii = 0; ii < 4; ++ii) {
                int gm = row0 + mi * 16 + quad * 4 + ii;
                if (gm < NN) {
                    float v = acc[mi][ni][ii] + bn;
                    h2[(size_t)gm * 256 + n] = f2b(fmaxf(v, 0.f));
                }
            }
        }
    }
}

// ---------------- pooling via run-length reduction (batch is SORTED)
#define PN 64
__global__ __launch_bounds__(256) void pool_rle(const int* __restrict__ batch,
                                                const bf16* __restrict__ H,
                                                float* __restrict__ pool,
                                                float* __restrict__ gcnt) {
    int t = threadIdx.x;               // feature dim
    int n0 = blockIdx.x * PN;
    int nend = n0 + PN; if (nend > NN) nend = NN;
    int curg = batch[n0];
    float acc = 0.f, cnt = 0.f;
    for (int n = n0; n < nend; ++n) {
        int g = batch[n];              // wave-uniform
        if (g != curg) {
            atomicAdd(&pool[(size_t)curg * 256 + t], acc);
            if (t == 0) atomicAdd(&gcnt[curg], cnt);
            acc = 0.f; cnt = 0.f; curg = g;
        }
        acc += b2f(H[(size_t)n * 256 + t]);
        cnt += 1.f;
    }
    atomicAdd(&pool[(size_t)curg * 256 + t], acc);
    if (t == 0) atomicAdd(&gcnt[curg], cnt);
}

// ---------------- head: out[g][c] = (pool[g]/cnt[g]) @ lin_w + lin_b  (f32 out)
__global__ __launch_bounds__(256) void final_head(const float* __restrict__ pool,
                                                  const float* __restrict__ gcnt,
                                                  const float* __restrict__ lin_w,
                                                  const float* __restrict__ lin_b,
                                                  float* __restrict__ out) {
    __shared__ float sm[256];
    int g = blockIdx.x, t = threadIdx.x;
    float inv = 1.0f / fmaxf(gcnt[g], 1.0f);
    sm[t] = pool[(size_t)g * 256 + t] * inv;
    __syncthreads();
    if (t < NCLS) {
        float s = lin_b[t];
        for (int d = 0; d < 256; ++d) s += sm[d] * lin_w[d * NCLS + t];
        out[g * NCLS + t] = s;
    }
}

extern "C" void kernel_launch(void* const* d_in, const int* in_sizes, int n_in,
                              void* d_out, int out_size, void* d_ws, size_t ws_size,
                              hipStream_t stream) {
    const int*   s_idx = (const int*)d_in[0];
    const int*   c_idx = (const int*)d_in[1];
    const int*   p_idx = (const int*)d_in[2];
    const int*   ei    = (const int*)d_in[3];   // (2, NE)
    const int*   et    = (const int*)d_in[4];
    const int*   batch = (const int*)d_in[5];
    const float* se    = (const float*)d_in[6];
    const float* ce    = (const float*)d_in[7];
    const float* pe    = (const float*)d_in[8];
    const float* W1    = (const float*)d_in[9];   // (3, 384, 256)
    const float* root1 = (const float*)d_in[10];  // (384, 256)
    const float* b1    = (const float*)d_in[11];
    const float* W2    = (const float*)d_in[12];  // (3, 256, 256)
    const float* root2 = (const float*)d_in[13];  // (256, 256)
    const float* b2    = (const float*)d_in[14];
    const float* lin_w = (const float*)d_in[15];
    const float* lin_b = (const float*)d_in[16];
    float* out = (float*)d_out;

    // ---- workspace carve-up (~172 MB; ws_size >= 190 MB confirmed in round 6)
    char* w = (char*)d_ws;
    size_t o = 0;
    auto alloc = [&](size_t bytes) -> void* {
        o = (o + 15) & ~(size_t)15;
        void* ptr = w + o;
        o += bytes;
        return ptr;
    };
    bf16*  hagg   = (bf16*) alloc((size_t)NN * 768 * 2);   // 76.8 MB
    bf16*  h1     = (bf16*) alloc((size_t)NN * 256 * 2);
    bf16*  h2     = (bf16*) alloc((size_t)NN * 256 * 2);
    bf16*  comb   = (bf16*) alloc((size_t)4 * NCMB * 256 * 2);
    int*   combo  = (int*)  alloc((size_t)NN * 4);
    int*   eidx   = (int*)  alloc((size_t)NE * 4);
    int*   cnt    = (int*)  alloc((size_t)NB * 4);
    int*   off    = (int*)  alloc((size_t)(NB + 1) * 4);
    int*   cursor = (int*)  alloc((size_t)NB * 4);
    int*   bsum   = (int*)  alloc((size_t)NBLK * 4);
    int*   bbase  = (int*)  alloc((size_t)NBLK * 4);
    float* tab    = (float*)alloc((size_t)4 * 144 * 256 * 4);
    bf16*  W2t    = (bf16*) alloc((size_t)256 * 1024 * 2);
    float* pool   = (float*)alloc((size_t)NG * 256 * 4);
    float* gcnt   = (float*)alloc((size_t)NG * 4);
    (void)ws_size;

    // ---- CSR build
    zero_u32<<<(NB + 255) / 256, 256, 0, stream>>>((unsigned*)cnt, NB);
    count_edges<<<(NE + 255) / 256, 256, 0, stream>>>(ei, et, cnt);
    scan_block_sums<<<NBLK, 256, 0, stream>>>(cnt, bsum);
    scan_base<<<1, 64, 0, stream>>>(bsum, bbase, off);
    scan_write<<<NBLK, 256, 0, stream>>>(cnt, bbase, off, cursor);
    scatter_edges<<<(NE + 255) / 256, 256, 0, stream>>>(ei, et, cursor, eidx);

    // ---- weight/table prep
    tab_gemm<<<4 * 144, 256, 0, stream>>>(se, ce, pe, W1, root1, tab);
    node_combo<<<(NN + 255) / 256, 256, 0, stream>>>(s_idx, c_idx, p_idx, combo);
    comb_build<<<4 * NCMB, 256, 0, stream>>>(tab, b1, comb);
    conv_w2cat<<<(256 * 1024 + 255) / 256, 256, 0, stream>>>(W2, root2, W2t);

    // ---- layer 1: fully fused combo-table gather
    l1_fused<<<(NN + 3) / 4, 256, 0, stream>>>(off, eidx, combo, comb, h1);

    // ---- layer 2: aggregate-first, then one barrier-free concat GEMM (bias+relu fused)
    agg_all<<<(NN + 3) / 4, 256, 0, stream>>>(off, eidx, h1, hagg);
    gemm_cat<<<(NN + 31) / 32, 256, 0, stream>>>(hagg, h1, W2t, b2, h2);

    // ---- pool + head
    zero_u32<<<(NG * 256 + NG + 255) / 256, 256, 0, stream>>>((unsigned*)pool, NG * 256 + NG);
    pool_rle<<<(NN + PN - 1) / PN, 256, 0, stream>>>(batch, h2, pool, gcnt);
    final_head<<<NG, 256, 0, stream>>>(pool, gcnt, lin_w, lin_b, out);
}

// Round 10
// 439.289 us; speedup vs baseline: 1.2185x; 1.2185x over previous
//
#include <hip/hip_runtime.h>
#include <hip/hip_bf16.h>

#define NN 50000          // nodes
#define NE 800000         // edges
#define NR 3              // relations
#define NG 500            // graphs
#define NB (NN * NR)      // (dst, rel) buckets = 150000
#define NCLS 10
#define NCMB 8192         // 8 shapes * 8 colors * 128 positions
#define CHUNK 2048        // scan elements per block
#define NBLK ((NB + CHUNK - 1) / CHUNK)   // 74

typedef __hip_bfloat16 bf16;
typedef __attribute__((ext_vector_type(8))) short short8;   // bf16x8 MFMA frag
typedef __attribute__((ext_vector_type(4))) float floatx4;  // MFMA accumulator

static __device__ __forceinline__ float b2f(bf16 x) { return __bfloat162float(x); }
static __device__ __forceinline__ bf16  f2b(float x) { return __float2bfloat16(x); }
static __device__ __forceinline__ float bs2f(short x) {
    return __bfloat162float(*reinterpret_cast<const bf16*>(&x));
}
static __device__ __forceinline__ short f2bs(float x) {
    bf16 b = __float2bfloat16(x);
    return *reinterpret_cast<const short*>(&b);
}

// ---------------- zero words (graph-capture-safe)
__global__ __launch_bounds__(256) void zero_u32(unsigned* __restrict__ p, long n) {
    long i = (long)blockIdx.x * 256 + threadIdx.x;
    if (i < n) p[i] = 0u;
}

// ---------------- per-(dst,rel) edge counts
__global__ __launch_bounds__(256) void count_edges(const int* __restrict__ ei,
                                                   const int* __restrict__ et,
                                                   int* __restrict__ cnt) {
    int e = blockIdx.x * 256 + threadIdx.x;
    if (e >= NE) return;
    atomicAdd(&cnt[ei[NE + e] * NR + et[e]], 1);
}

// ---------------- counting-sort scan, phase A: per-block (2048-elem) totals
__global__ __launch_bounds__(256) void scan_block_sums(const int* __restrict__ cnt,
                                                       int* __restrict__ bsum) {
    __shared__ int sm[256];
    int b = blockIdx.x, t = threadIdx.x;
    int base = b * CHUNK + t * 8, s = 0;
#pragma unroll
    for (int j = 0; j < 8; ++j) { int i = base + j; if (i < NB) s += cnt[i]; }
    sm[t] = s; __syncthreads();
    for (int st = 128; st; st >>= 1) { if (t < st) sm[t] += sm[t + st]; __syncthreads(); }
    if (!t) bsum[b] = sm[0];
}

// ---------------- phase B: exclusive scan of the 74 block sums
__global__ void scan_base(const int* __restrict__ bsum, int* __restrict__ bbase,
                          int* __restrict__ off) {
    if (threadIdx.x == 0 && blockIdx.x == 0) {
        int run = 0;
        for (int i = 0; i < NBLK; ++i) { bbase[i] = run; run += bsum[i]; }
        off[NB] = run;   // == NE
    }
}

// ---------------- phase C: in-block exclusive scan + base -> off[], cursor[]
__global__ __launch_bounds__(256) void scan_write(const int* __restrict__ cnt,
                                                  const int* __restrict__ bbase,
                                                  int* __restrict__ off,
                                                  int* __restrict__ cursor) {
    int b = blockIdx.x, t = threadIdx.x;
    int base = b * CHUNK + t * 8;
    int v[8], ts = 0;
#pragma unroll
    for (int j = 0; j < 8; ++j) { int i = base + j; v[j] = (i < NB) ? cnt[i] : 0; ts += v[j]; }
    int lane = t & 63, wv = t >> 6;
    int incl = ts;
    for (int d = 1; d < 64; d <<= 1) {
        int o = __shfl_up(incl, d, 64);
        if (lane >= d) incl += o;
    }
    __shared__ int wsum[4];
    if (lane == 63) wsum[wv] = incl;
    __syncthreads();
    int wbase = 0;
    for (int w = 0; w < wv; ++w) wbase += wsum[w];
    int run = bbase[b] + wbase + incl - ts;
#pragma unroll
    for (int j = 0; j < 8; ++j) {
        int i = base + j;
        if (i < NB) { off[i] = run; cursor[i] = run; }
        run += v[j];
    }
}

// ---------------- bucket-sort edges: stores src AND combo[src] (kills a dependent
// load level in the l1 gather loop)
__global__ __launch_bounds__(256) void scatter_edges(const int* __restrict__ ei,
                                                     const int* __restrict__ et,
                                                     const int* __restrict__ combo,
                                                     int* __restrict__ cursor,
                                                     int* __restrict__ eidx,
                                                     int* __restrict__ ecmb) {
    int e = blockIdx.x * 256 + threadIdx.x;
    if (e >= NE) return;
    int b = ei[NE + e] * NR + et[e];
    int pos = atomicAdd(&cursor[b], 1);
    int s = ei[e];
    eidx[pos] = s;
    ecmb[pos] = combo[s];
}

// ---------------- layer-1 tables: tab[r][row][n], r in 0..3 (3 rels + root)
__global__ __launch_bounds__(256) void tab_gemm(const float* __restrict__ se,
                                                const float* __restrict__ ce,
                                                const float* __restrict__ pe,
                                                const float* __restrict__ W1,
                                                const float* __restrict__ root1,
                                                float* __restrict__ tab) {
    int bid = blockIdx.x;              // 4*144 blocks
    int r = bid / 144, row = bid % 144;
    int t = threadIdx.x;               // output column 0..255
    const float* A; int segk;
    if (row < 8)       { A = se + row * 128;        segk = 0; }
    else if (row < 16) { A = ce + (row - 8) * 128;  segk = 128; }
    else               { A = pe + (row - 16) * 128; segk = 256; }
    const float* W = (r < 3) ? (W1 + (size_t)r * 384 * 256) : root1;
    float acc = 0.f;
    for (int k = 0; k < 128; ++k)
        acc += A[k] * W[(size_t)(segk + k) * 256 + t];
    tab[((size_t)r * 144 + row) * 256 + t] = acc;
}

// ---------------- node combo ids: combo[n] = s*1024 + c*128 + p
__global__ __launch_bounds__(256) void node_combo(const int* __restrict__ s,
                                                  const int* __restrict__ c,
                                                  const int* __restrict__ p,
                                                  int* __restrict__ combo) {
    int n = blockIdx.x * 256 + threadIdx.x;
    if (n < NN) combo[n] = (s[n] << 10) | (c[n] << 7) | p[n];
}

// ---------------- comb[r][cmb][d] = tab[r][s]+tab[r][8+c]+tab[r][16+p] (+b1 for r=3), bf16
__global__ __launch_bounds__(256) void comb_build(const float* __restrict__ tab,
                                                  const float* __restrict__ b1,
                                                  bf16* __restrict__ comb) {
    int bid = blockIdx.x;              // 4*8192
    int r = bid >> 13, cmb = bid & (NCMB - 1);
    int d = threadIdx.x;
    int si = cmb >> 10, ci = (cmb >> 7) & 7, pi = cmb & 127;
    const float* tr = tab + (size_t)r * 144 * 256;
    float v = tr[si * 256 + d] + tr[(8 + ci) * 256 + d] + tr[(16 + pi) * 256 + d];
    if (r == 3) v += b1[d];
    comb[(size_t)bid * 256 + d] = f2b(v);
}

// ---------------- fused layer 1: 4 waves/block, 1 wave/dst.
// Lane-split gather; ecmb gives combo directly (1 dependent load level).
__global__ __launch_bounds__(256) void l1_fused(const int* __restrict__ off,
                                                const int* __restrict__ ecmb,
                                                const int* __restrict__ combo,
                                                const bf16* __restrict__ comb,
                                                bf16* __restrict__ h1) {
    int wave = threadIdx.x >> 6, lane = threadIdx.x & 63;
    int dst = blockIdx.x * 4 + wave;
    if (dst >= NN) return;
    int half = lane >> 5, li8 = (lane & 31) * 8;
    float acc[8];
    if (half == 0) {   // root slice (b1 pre-folded); only half0's acc is used
        int cmbD = combo[dst];
        short8 rv = *(const short8*)(comb + ((size_t)(3 * NCMB) + cmbD) * 256 + li8);
#pragma unroll
        for (int i = 0; i < 8; ++i) acc[i] = bs2f(rv[i]);
    } else {
#pragma unroll
        for (int i = 0; i < 8; ++i) acc[i] = 0.f;
    }
    for (int r = 0; r < NR; ++r) {
        int lo = off[dst * NR + r], hi = off[dst * NR + r + 1];
        if (hi <= lo) continue;                 // empty bucket contributes 0 (matches ref)
        const bf16* cr = comb + (size_t)r * NCMB * 256;
        float s[8] = {};
        int j = lo;
        for (; j + 8 <= hi; j += 8) {           // 4 rows/half in flight
            int c0 = ecmb[j + half],     c1 = ecmb[j + 2 + half];
            int c2 = ecmb[j + 4 + half], c3 = ecmb[j + 6 + half];
            short8 v0 = *(const short8*)(cr + (size_t)c0 * 256 + li8);
            short8 v1 = *(const short8*)(cr + (size_t)c1 * 256 + li8);
            short8 v2 = *(const short8*)(cr + (size_t)c2 * 256 + li8);
            short8 v3 = *(const short8*)(cr + (size_t)c3 * 256 + li8);
#pragma unroll
            for (int i = 0; i < 8; ++i)
                s[i] += (bs2f(v0[i]) + bs2f(v1[i])) + (bs2f(v2[i]) + bs2f(v3[i]));
        }
        for (; j + 2 <= hi; j += 2) {
            int c0 = ecmb[j + half];
            short8 v0 = *(const short8*)(cr + (size_t)c0 * 256 + li8);
#pragma unroll
            for (int i = 0; i < 8; ++i) s[i] += bs2f(v0[i]);
        }
        if (j < hi && half == 0) {              // odd remainder
            short8 v0 = *(const short8*)(cr + (size_t)ecmb[j] * 256 + li8);
#pragma unroll
            for (int i = 0; i < 8; ++i) s[i] += bs2f(v0[i]);
        }
        float inv = 1.0f / (float)(hi - lo);
#pragma unroll
        for (int i = 0; i < 8; ++i) {
            float tot = s[i] + __shfl_xor(s[i], 32);
            if (half == 0) acc[i] += tot * inv;
        }
    }
    if (half == 0) {
        short8 o;
#pragma unroll
        for (int i = 0; i < 8; ++i) o[i] = f2bs(fmaxf(acc[i], 0.f));
        *(short8*)(h1 + (size_t)dst * 256 + li8) = o;
    }
}

// ---------------- per-relation mean aggregation of h1 (aggregate BEFORE transform):
// hagg[dst][r*256+d] = mean_{src in bucket(dst,r)} h1[src][d]   (0 if empty)
__global__ __launch_bounds__(256) void agg_all(const int* __restrict__ off,
                                               const int* __restrict__ eidx,
                                               const bf16* __restrict__ h1,
                                               bf16* __restrict__ hagg) {
    int wave = threadIdx.x >> 6, lane = threadIdx.x & 63;
    int dst = blockIdx.x * 4 + wave;
    if (dst >= NN) return;
    int half = lane >> 5, li8 = (lane & 31) * 8;
    for (int r = 0; r < NR; ++r) {
        int lo = off[dst * NR + r], hi = off[dst * NR + r + 1];
        float s[8] = {};
        int j = lo;
        for (; j + 8 <= hi; j += 8) {           // 4 rows/half in flight
            int e0 = eidx[j + half],     e1 = eidx[j + 2 + half];
            int e2 = eidx[j + 4 + half], e3 = eidx[j + 6 + half];
            short8 v0 = *(const short8*)(h1 + (size_t)e0 * 256 + li8);
            short8 v1 = *(const short8*)(h1 + (size_t)e1 * 256 + li8);
            short8 v2 = *(const short8*)(h1 + (size_t)e2 * 256 + li8);
            short8 v3 = *(const short8*)(h1 + (size_t)e3 * 256 + li8);
#pragma unroll
            for (int i = 0; i < 8; ++i)
                s[i] += (bs2f(v0[i]) + bs2f(v1[i])) + (bs2f(v2[i]) + bs2f(v3[i]));
        }
        for (; j + 2 <= hi; j += 2) {
            int e0 = eidx[j + half];
            short8 v0 = *(const short8*)(h1 + (size_t)e0 * 256 + li8);
#pragma unroll
            for (int i = 0; i < 8; ++i) s[i] += bs2f(v0[i]);
        }
        if (j < hi && half == 0) {
            short8 v0 = *(const short8*)(h1 + (size_t)eidx[j] * 256 + li8);
#pragma unroll
            for (int i = 0; i < 8; ++i) s[i] += bs2f(v0[i]);
        }
        float inv = (hi > lo) ? 1.0f / (float)(hi - lo) : 0.f;
        short8 o;
#pragma unroll
        for (int i = 0; i < 8; ++i) {
            float tot = s[i] + __shfl_xor(s[i], 32);
            o[i] = f2bs(tot * inv);
        }
        if (half == 0)
            *(short8*)(hagg + (size_t)dst * 768 + r * 256 + li8) = o;
    }
}

// ---------------- W2cat -> bf16, transposed on K: Wt[n][k], k = [W2_0;W2_1;W2_2;root2]
__global__ __launch_bounds__(256) void conv_w2cat(const float* __restrict__ W2,
                                                  const float* __restrict__ root2,
                                                  bf16* __restrict__ Wt) {
    int idx = blockIdx.x * 256 + threadIdx.x;   // 256*1024
    if (idx >= 256 * 1024) return;
    int n = idx >> 10, k = idx & 1023;
    float v = (k < 768) ? W2[((size_t)(k >> 8) * 256 + (k & 255)) * 256 + n]
                        : root2[(size_t)(k - 768) * 256 + n];
    Wt[idx] = f2b(v);
}

// ---------------- concat MFMA GEMM v4: round-8 LDS double-buffer + 3-deep
// register pipeline. h2[M][256] = relu( [hagg | h1] (M x 1024) @ Wt^T + b2 )
// 64x128 tile, 4 waves (each 32 rows x 64 cols = 2x4 MFMA grid).
// Chunk c(i+3) is issued at step i and consumed (reg->LDS) at end of step i+2,
// giving ~2.7 K-steps of HBM-latency cover (vs 1 step in round 8).
__global__ __launch_bounds__(256) void gemm_cat(const bf16* __restrict__ hagg,
                                                const bf16* __restrict__ h1,
                                                const bf16* __restrict__ Wt,
                                                const float* __restrict__ bias,
                                                bf16* __restrict__ h2) {
    __shared__ short As[2][64 * 40];    // 10.2 KB  (row stride 40 shorts = 80 B)
    __shared__ short Bs[2][128 * 40];   // 20.5 KB
    const int t = threadIdx.x;
    const int wave = t >> 6, lane = t & 63;
    const int quad = lane >> 4, l16 = lane & 15;
    const int mq = (wave & 1) * 32;     // wave's 32-row m-range
    const int nq = (wave >> 1) * 64;    // wave's 64-col n-range
    const int row0 = blockIdx.y * 64, col0 = blockIdx.x * 128;
    const int sr = t >> 2;              // staging row 0..63
    const int sp = (t & 3) * 8;         // staging k-offset {0,8,16,24}
    const int gmA = row0 + sr;

    auto loadA = [&](int k0) -> short8 {
        short8 v = {};
        int k = k0 + sp;
        if (gmA < NN)
            v = (k < 768) ? *(const short8*)(hagg + (size_t)gmA * 768 + k)
                          : *(const short8*)(h1 + (size_t)gmA * 256 + (k - 768));
        return v;
    };
    auto loadB = [&](int k0, int rlocal) -> short8 {
        return *(const short8*)(Wt + (size_t)(col0 + rlocal) * 1024 + k0 + sp);
    };

    floatx4 acc[2][4] = {};
    short8 ra[3], rb0[3], rb1[3];

    // prologue: 3 chunks in flight; chunk 0 staged to LDS buffer 0
#pragma unroll
    for (int s = 0; s < 3; ++s) {
        ra[s] = loadA(s * 32); rb0[s] = loadB(s * 32, sr); rb1[s] = loadB(s * 32, sr + 64);
    }
    *(short8*)&As[0][sr * 40 + sp] = ra[0];
    *(short8*)&Bs[0][sr * 40 + sp] = rb0[0];
    *(short8*)&Bs[0][(sr + 64) * 40 + sp] = rb1[0];
    __syncthreads();

#pragma unroll
    for (int i = 0; i < 32; ++i) {
        const int cur = i & 1, alt = 1 - cur;
        const int fs = i % 3;               // freed set -> receives c(i+3)
        if (i + 3 < 32) {
            int k0 = (i + 3) * 32;
            ra[fs] = loadA(k0); rb0[fs] = loadB(k0, sr); rb1[fs] = loadB(k0, sr + 64);
        }
        short8 af[2], bfr[4];
#pragma unroll
        for (int mi = 0; mi < 2; ++mi)
            af[mi] = *(const short8*)&As[cur][(mq + mi * 16 + l16) * 40 + quad * 8];
#pragma unroll
        for (int ni = 0; ni < 4; ++ni)
            bfr[ni] = *(const short8*)&Bs[cur][(nq + ni * 16 + l16) * 40 + quad * 8];
#pragma unroll
        for (int mi = 0; mi < 2; ++mi)
#pragma unroll
            for (int ni = 0; ni < 4; ++ni)
                acc[mi][ni] = __builtin_amdgcn_mfma_f32_16x16x32_bf16(
                    af[mi], bfr[ni], acc[mi][ni], 0, 0, 0);
        if (i + 1 < 32) {                   // stage c(i+1) (loaded 2 steps ago)
            const int ws = (i + 1) % 3;
            *(short8*)&As[alt][sr * 40 + sp] = ra[ws];
            *(short8*)&Bs[alt][sr * 40 + sp] = rb0[ws];
            *(short8*)&Bs[alt][(sr + 64) * 40 + sp] = rb1[ws];
        }
        __syncthreads();
    }

    // C/D layout: col = lane&15, row = quad*4 + reg   [m89/m91-verified]
#pragma unroll
    for (int mi = 0; mi < 2; ++mi) {
#pragma unroll
        for (int ni = 0; ni < 4; ++ni) {
            int n = col0 + nq + ni * 16 + l16;
            float bn = bias[n];
#pragma unroll
            for (int ii = 0; ii < 4; ++ii) {
                int gm = row0 + mq + mi * 16 + quad * 4 + ii;
                if (gm < NN) {
                    float v = acc[mi][ni][ii] + bn;
                    h2[(size_t)gm * 256 + n] = f2b(fmaxf(v, 0.f));
                }
            }
        }
    }
}

// ---------------- pooling via run-length reduction (batch is SORTED)
#define PN 64
__global__ __launch_bounds__(256) void pool_rle(const int* __restrict__ batch,
                                                const bf16* __restrict__ H,
                                                float* __restrict__ pool,
                                                float* __restrict__ gcnt) {
    int t = threadIdx.x;               // feature dim
    int n0 = blockIdx.x * PN;
    int nend = n0 + PN; if (nend > NN) nend = NN;
    int curg = batch[n0];
    float acc = 0.f, cnt = 0.f;
    for (int n = n0; n < nend; ++n) {
        int g = batch[n];              // wave-uniform
        if (g != curg) {
            atomicAdd(&pool[(size_t)curg * 256 + t], acc);
            if (t == 0) atomicAdd(&gcnt[curg], cnt);
            acc = 0.f; cnt = 0.f; curg = g;
        }
        acc += b2f(H[(size_t)n * 256 + t]);
        cnt += 1.f;
    }
    atomicAdd(&pool[(size_t)curg * 256 + t], acc);
    if (t == 0) atomicAdd(&gcnt[curg], cnt);
}

// ---------------- head: out[g][c] = (pool[g]/cnt[g]) @ lin_w + lin_b  (f32 out)
__global__ __launch_bounds__(256) void final_head(const float* __restrict__ pool,
                                                  const float* __restrict__ gcnt,
                                                  const float* __restrict__ lin_w,
                                                  const float* __restrict__ lin_b,
                                                  float* __restrict__ out) {
    __shared__ float sm[256];
    int g = blockIdx.x, t = threadIdx.x;
    float inv = 1.0f / fmaxf(gcnt[g], 1.0f);
    sm[t] = pool[(size_t)g * 256 + t] * inv;
    __syncthreads();
    if (t < NCLS) {
        float s = lin_b[t];
        for (int d = 0; d < 256; ++d) s += sm[d] * lin_w[d * NCLS + t];
        out[g * NCLS + t] = s;
    }
}

extern "C" void kernel_launch(void* const* d_in, const int* in_sizes, int n_in,
                              void* d_out, int out_size, void* d_ws, size_t ws_size,
                              hipStream_t stream) {
    const int*   s_idx = (const int*)d_in[0];
    const int*   c_idx = (const int*)d_in[1];
    const int*   p_idx = (const int*)d_in[2];
    const int*   ei    = (const int*)d_in[3];   // (2, NE)
    const int*   et    = (const int*)d_in[4];
    const int*   batch = (const int*)d_in[5];
    const float* se    = (const float*)d_in[6];
    const float* ce    = (const float*)d_in[7];
    const float* pe    = (const float*)d_in[8];
    const float* W1    = (const float*)d_in[9];   // (3, 384, 256)
    const float* root1 = (const float*)d_in[10];  // (384, 256)
    const float* b1    = (const float*)d_in[11];
    const float* W2    = (const float*)d_in[12];  // (3, 256, 256)
    const float* root2 = (const float*)d_in[13];  // (256, 256)
    const float* b2    = (const float*)d_in[14];
    const float* lin_w = (const float*)d_in[15];
    const float* lin_b = (const float*)d_in[16];
    float* out = (float*)d_out;

    // ---- workspace carve-up (~175 MB; ws_size >= 190 MB confirmed in round 6)
    char* w = (char*)d_ws;
    size_t o = 0;
    auto alloc = [&](size_t bytes) -> void* {
        o = (o + 15) & ~(size_t)15;
        void* ptr = w + o;
        o += bytes;
        return ptr;
    };
    bf16*  hagg   = (bf16*) alloc((size_t)NN * 768 * 2);   // 76.8 MB
    bf16*  h1     = (bf16*) alloc((size_t)NN * 256 * 2);
    bf16*  h2     = (bf16*) alloc((size_t)NN * 256 * 2);
    bf16*  comb   = (bf16*) alloc((size_t)4 * NCMB * 256 * 2);
    int*   combo  = (int*)  alloc((size_t)NN * 4);
    int*   eidx   = (int*)  alloc((size_t)NE * 4);
    int*   ecmb   = (int*)  alloc((size_t)NE * 4);
    int*   cnt    = (int*)  alloc((size_t)NB * 4);
    int*   off    = (int*)  alloc((size_t)(NB + 1) * 4);
    int*   cursor = (int*)  alloc((size_t)NB * 4);
    int*   bsum   = (int*)  alloc((size_t)NBLK * 4);
    int*   bbase  = (int*)  alloc((size_t)NBLK * 4);
    float* tab    = (float*)alloc((size_t)4 * 144 * 256 * 4);
    bf16*  W2t    = (bf16*) alloc((size_t)256 * 1024 * 2);
    float* pool   = (float*)alloc((size_t)NG * 256 * 4);
    float* gcnt   = (float*)alloc((size_t)NG * 4);
    (void)ws_size;

    // ---- CSR build (node_combo first: scatter_edges materializes ecmb)
    node_combo<<<(NN + 255) / 256, 256, 0, stream>>>(s_idx, c_idx, p_idx, combo);
    zero_u32<<<(NB + 255) / 256, 256, 0, stream>>>((unsigned*)cnt, NB);
    count_edges<<<(NE + 255) / 256, 256, 0, stream>>>(ei, et, cnt);
    scan_block_sums<<<NBLK, 256, 0, stream>>>(cnt, bsum);
    scan_base<<<1, 64, 0, stream>>>(bsum, bbase, off);
    scan_write<<<NBLK, 256, 0, stream>>>(cnt, bbase, off, cursor);
    scatter_edges<<<(NE + 255) / 256, 256, 0, stream>>>(ei, et, combo, cursor, eidx, ecmb);

    // ---- weight/table prep
    tab_gemm<<<4 * 144, 256, 0, stream>>>(se, ce, pe, W1, root1, tab);
    comb_build<<<4 * NCMB, 256, 0, stream>>>(tab, b1, comb);
    conv_w2cat<<<(256 * 1024 + 255) / 256, 256, 0, stream>>>(W2, root2, W2t);

    // ---- layer 1: fully fused combo-table gather
    l1_fused<<<(NN + 3) / 4, 256, 0, stream>>>(off, ecmb, combo, comb, h1);

    // ---- layer 2: aggregate-first, then one concat GEMM with fused bias+relu
    agg_all<<<(NN + 3) / 4, 256, 0, stream>>>(off, eidx, h1, hagg);
    dim3 g2(2, (NN + 63) / 64);
    gemm_cat<<<g2, 256, 0, stream>>>(hagg, h1, W2t, b2, h2);

    // ---- pool + head
    zero_u32<<<(NG * 256 + NG + 255) / 256, 256, 0, stream>>>((unsigned*)pool, NG * 256 + NG);
    pool_rle<<<(NN + PN - 1) / PN, 256, 0, stream>>>(batch, h2, pool, gcnt);
    final_head<<<NG, 256, 0, stream>>>(pool, gcnt, lin_w, lin_b, out);
}

// Round 11
// 434.946 us; speedup vs baseline: 1.2306x; 1.0100x over previous
//
#include <hip/hip_runtime.h>
#include <hip/hip_bf16.h>

#define NN 50000          // nodes
#define NE 800000         // edges
#define NR 3              // relations
#define NG 500            // graphs
#define NB (NN * NR)      // (dst, rel) buckets = 150000
#define NCLS 10
#define NCMB 8192         // 8 shapes * 8 colors * 128 positions
#define CHUNK 2048        // scan elements per block
#define NBLK ((NB + CHUNK - 1) / CHUNK)   // 74

typedef __hip_bfloat16 bf16;
typedef __attribute__((ext_vector_type(8))) short short8;   // bf16x8 MFMA frag
typedef __attribute__((ext_vector_type(4))) float floatx4;  // MFMA accumulator

static __device__ __forceinline__ float b2f(bf16 x) { return __bfloat162float(x); }
static __device__ __forceinline__ bf16  f2b(float x) { return __float2bfloat16(x); }
static __device__ __forceinline__ float bs2f(short x) {
    return __bfloat162float(*reinterpret_cast<const bf16*>(&x));
}
static __device__ __forceinline__ short f2bs(float x) {
    bf16 b = __float2bfloat16(x);
    return *reinterpret_cast<const short*>(&b);
}

// ---------------- zero words (graph-capture-safe)
__global__ __launch_bounds__(256) void zero_u32(unsigned* __restrict__ p, long n) {
    long i = (long)blockIdx.x * 256 + threadIdx.x;
    if (i < n) p[i] = 0u;
}

// ---------------- per-(dst,rel) edge counts
__global__ __launch_bounds__(256) void count_edges(const int* __restrict__ ei,
                                                   const int* __restrict__ et,
                                                   int* __restrict__ cnt) {
    int e = blockIdx.x * 256 + threadIdx.x;
    if (e >= NE) return;
    atomicAdd(&cnt[ei[NE + e] * NR + et[e]], 1);
}

// ---------------- counting-sort scan, phase A: per-block (2048-elem) totals
__global__ __launch_bounds__(256) void scan_block_sums(const int* __restrict__ cnt,
                                                       int* __restrict__ bsum) {
    __shared__ int sm[256];
    int b = blockIdx.x, t = threadIdx.x;
    int base = b * CHUNK + t * 8, s = 0;
#pragma unroll
    for (int j = 0; j < 8; ++j) { int i = base + j; if (i < NB) s += cnt[i]; }
    sm[t] = s; __syncthreads();
    for (int st = 128; st; st >>= 1) { if (t < st) sm[t] += sm[t + st]; __syncthreads(); }
    if (!t) bsum[b] = sm[0];
}

// ---------------- phase B: exclusive scan of the 74 block sums
__global__ void scan_base(const int* __restrict__ bsum, int* __restrict__ bbase,
                          int* __restrict__ off) {
    if (threadIdx.x == 0 && blockIdx.x == 0) {
        int run = 0;
        for (int i = 0; i < NBLK; ++i) { bbase[i] = run; run += bsum[i]; }
        off[NB] = run;   // == NE
    }
}

// ---------------- phase C: in-block exclusive scan + base -> off[], cursor[]
__global__ __launch_bounds__(256) void scan_write(const int* __restrict__ cnt,
                                                  const int* __restrict__ bbase,
                                                  int* __restrict__ off,
                                                  int* __restrict__ cursor) {
    int b = blockIdx.x, t = threadIdx.x;
    int base = b * CHUNK + t * 8;
    int v[8], ts = 0;
#pragma unroll
    for (int j = 0; j < 8; ++j) { int i = base + j; v[j] = (i < NB) ? cnt[i] : 0; ts += v[j]; }
    int lane = t & 63, wv = t >> 6;
    int incl = ts;
    for (int d = 1; d < 64; d <<= 1) {
        int o = __shfl_up(incl, d, 64);
        if (lane >= d) incl += o;
    }
    __shared__ int wsum[4];
    if (lane == 63) wsum[wv] = incl;
    __syncthreads();
    int wbase = 0;
    for (int w = 0; w < wv; ++w) wbase += wsum[w];
    int run = bbase[b] + wbase + incl - ts;
#pragma unroll
    for (int j = 0; j < 8; ++j) {
        int i = base + j;
        if (i < NB) { off[i] = run; cursor[i] = run; }
        run += v[j];
    }
}

// ---------------- bucket-sort edges: stores src AND combo[src]
__global__ __launch_bounds__(256) void scatter_edges(const int* __restrict__ ei,
                                                     const int* __restrict__ et,
                                                     const int* __restrict__ combo,
                                                     int* __restrict__ cursor,
                                                     int* __restrict__ eidx,
                                                     int* __restrict__ ecmb) {
    int e = blockIdx.x * 256 + threadIdx.x;
    if (e >= NE) return;
    int b = ei[NE + e] * NR + et[e];
    int pos = atomicAdd(&cursor[b], 1);
    int s = ei[e];
    eidx[pos] = s;
    ecmb[pos] = combo[s];
}

// ---------------- layer-1 tables: tab[r][row][n], r in 0..3 (3 rels + root)
__global__ __launch_bounds__(256) void tab_gemm(const float* __restrict__ se,
                                                const float* __restrict__ ce,
                                                const float* __restrict__ pe,
                                                const float* __restrict__ W1,
                                                const float* __restrict__ root1,
                                                float* __restrict__ tab) {
    int bid = blockIdx.x;              // 4*144 blocks
    int r = bid / 144, row = bid % 144;
    int t = threadIdx.x;               // output column 0..255
    const float* A; int segk;
    if (row < 8)       { A = se + row * 128;        segk = 0; }
    else if (row < 16) { A = ce + (row - 8) * 128;  segk = 128; }
    else               { A = pe + (row - 16) * 128; segk = 256; }
    const float* W = (r < 3) ? (W1 + (size_t)r * 384 * 256) : root1;
    float acc = 0.f;
    for (int k = 0; k < 128; ++k)
        acc += A[k] * W[(size_t)(segk + k) * 256 + t];
    tab[((size_t)r * 144 + row) * 256 + t] = acc;
}

// ---------------- node combo ids: combo[n] = s*1024 + c*128 + p
__global__ __launch_bounds__(256) void node_combo(const int* __restrict__ s,
                                                  const int* __restrict__ c,
                                                  const int* __restrict__ p,
                                                  int* __restrict__ combo) {
    int n = blockIdx.x * 256 + threadIdx.x;
    if (n < NN) combo[n] = (s[n] << 10) | (c[n] << 7) | p[n];
}

// ---------------- comb[r][cmb][d] = tab[r][s]+tab[r][8+c]+tab[r][16+p] (+b1 for r=3), bf16
__global__ __launch_bounds__(256) void comb_build(const float* __restrict__ tab,
                                                  const float* __restrict__ b1,
                                                  bf16* __restrict__ comb) {
    int bid = blockIdx.x;              // 4*8192
    int r = bid >> 13, cmb = bid & (NCMB - 1);
    int d = threadIdx.x;
    int si = cmb >> 10, ci = (cmb >> 7) & 7, pi = cmb & 127;
    const float* tr = tab + (size_t)r * 144 * 256;
    float v = tr[si * 256 + d] + tr[(8 + ci) * 256 + d] + tr[(16 + pi) * 256 + d];
    if (r == 3) v += b1[d];
    comb[(size_t)bid * 256 + d] = f2b(v);
}

// ---------------- fused layer 1: 4 waves/block, 1 wave/dst, lane-split 8-deep gather
__global__ __launch_bounds__(256) void l1_fused(const int* __restrict__ off,
                                                const int* __restrict__ ecmb,
                                                const int* __restrict__ combo,
                                                const bf16* __restrict__ comb,
                                                bf16* __restrict__ h1) {
    int wave = threadIdx.x >> 6, lane = threadIdx.x & 63;
    int dst = blockIdx.x * 4 + wave;
    if (dst >= NN) return;
    int half = lane >> 5, li8 = (lane & 31) * 8;
    float acc[8];
    if (half == 0) {   // root slice (b1 pre-folded); only half0's acc is used
        int cmbD = combo[dst];
        short8 rv = *(const short8*)(comb + ((size_t)(3 * NCMB) + cmbD) * 256 + li8);
#pragma unroll
        for (int i = 0; i < 8; ++i) acc[i] = bs2f(rv[i]);
    } else {
#pragma unroll
        for (int i = 0; i < 8; ++i) acc[i] = 0.f;
    }
    for (int r = 0; r < NR; ++r) {
        int lo = off[dst * NR + r], hi = off[dst * NR + r + 1];
        if (hi <= lo) continue;                 // empty bucket contributes 0 (matches ref)
        const bf16* cr = comb + (size_t)r * NCMB * 256;
        float s[8] = {};
        int j = lo;
        for (; j + 8 <= hi; j += 8) {           // 4 rows/half in flight
            int c0 = ecmb[j + half],     c1 = ecmb[j + 2 + half];
            int c2 = ecmb[j + 4 + half], c3 = ecmb[j + 6 + half];
            short8 v0 = *(const short8*)(cr + (size_t)c0 * 256 + li8);
            short8 v1 = *(const short8*)(cr + (size_t)c1 * 256 + li8);
            short8 v2 = *(const short8*)(cr + (size_t)c2 * 256 + li8);
            short8 v3 = *(const short8*)(cr + (size_t)c3 * 256 + li8);
#pragma unroll
            for (int i = 0; i < 8; ++i)
                s[i] += (bs2f(v0[i]) + bs2f(v1[i])) + (bs2f(v2[i]) + bs2f(v3[i]));
        }
        for (; j + 2 <= hi; j += 2) {
            int c0 = ecmb[j + half];
            short8 v0 = *(const short8*)(cr + (size_t)c0 * 256 + li8);
#pragma unroll
            for (int i = 0; i < 8; ++i) s[i] += bs2f(v0[i]);
        }
        if (j < hi && half == 0) {              // odd remainder
            short8 v0 = *(const short8*)(cr + (size_t)ecmb[j] * 256 + li8);
#pragma unroll
            for (int i = 0; i < 8; ++i) s[i] += bs2f(v0[i]);
        }
        float inv = 1.0f / (float)(hi - lo);
#pragma unroll
        for (int i = 0; i < 8; ++i) {
            float tot = s[i] + __shfl_xor(s[i], 32);
            if (half == 0) acc[i] += tot * inv;
        }
    }
    if (half == 0) {
        short8 o;
#pragma unroll
        for (int i = 0; i < 8; ++i) o[i] = f2bs(fmaxf(acc[i], 0.f));
        *(short8*)(h1 + (size_t)dst * 256 + li8) = o;
    }
}

// ---------------- per-relation mean aggregation of h1:
// hagg[dst][r*256+d] = mean_{src in bucket(dst,r)} h1[src][d]   (0 if empty)
__global__ __launch_bounds__(256) void agg_all(const int* __restrict__ off,
                                               const int* __restrict__ eidx,
                                               const bf16* __restrict__ h1,
                                               bf16* __restrict__ hagg) {
    int wave = threadIdx.x >> 6, lane = threadIdx.x & 63;
    int dst = blockIdx.x * 4 + wave;
    if (dst >= NN) return;
    int half = lane >> 5, li8 = (lane & 31) * 8;
    for (int r = 0; r < NR; ++r) {
        int lo = off[dst * NR + r], hi = off[dst * NR + r + 1];
        float s[8] = {};
        int j = lo;
        for (; j + 8 <= hi; j += 8) {           // 4 rows/half in flight
            int e0 = eidx[j + half],     e1 = eidx[j + 2 + half];
            int e2 = eidx[j + 4 + half], e3 = eidx[j + 6 + half];
            short8 v0 = *(const short8*)(h1 + (size_t)e0 * 256 + li8);
            short8 v1 = *(const short8*)(h1 + (size_t)e1 * 256 + li8);
            short8 v2 = *(const short8*)(h1 + (size_t)e2 * 256 + li8);
            short8 v3 = *(const short8*)(h1 + (size_t)e3 * 256 + li8);
#pragma unroll
            for (int i = 0; i < 8; ++i)
                s[i] += (bs2f(v0[i]) + bs2f(v1[i])) + (bs2f(v2[i]) + bs2f(v3[i]));
        }
        for (; j + 2 <= hi; j += 2) {
            int e0 = eidx[j + half];
            short8 v0 = *(const short8*)(h1 + (size_t)e0 * 256 + li8);
#pragma unroll
            for (int i = 0; i < 8; ++i) s[i] += bs2f(v0[i]);
        }
        if (j < hi && half == 0) {
            short8 v0 = *(const short8*)(h1 + (size_t)eidx[j] * 256 + li8);
#pragma unroll
            for (int i = 0; i < 8; ++i) s[i] += bs2f(v0[i]);
        }
        float inv = (hi > lo) ? 1.0f / (float)(hi - lo) : 0.f;
        short8 o;
#pragma unroll
        for (int i = 0; i < 8; ++i) {
            float tot = s[i] + __shfl_xor(s[i], 32);
            o[i] = f2bs(tot * inv);
        }
        if (half == 0)
            *(short8*)(hagg + (size_t)dst * 768 + r * 256 + li8) = o;
    }
}

// ---------------- W2cat -> bf16 in MFMA-FRAGMENT ORDER:
// Wf element idx = (((colblk*32 + chunk)*4 + ni)*64 + lane)*8 + j  maps to
// Wt[col][k] with col = colblk*64 + ni*16 + (lane&15), k = chunk*32 + (lane>>4)*8 + j,
// where Wt[n][k] = concat(W2_0;W2_1;W2_2;root2)[k][n].
// A wave's B fragment is then ONE contiguous 1 KB segment (coalesced b128/lane).
__global__ __launch_bounds__(256) void conv_w2cat(const float* __restrict__ W2,
                                                  const float* __restrict__ root2,
                                                  bf16* __restrict__ Wf) {
    int idx = blockIdx.x * 256 + threadIdx.x;   // 256*1024 elements
    if (idx >= 256 * 1024) return;
    int j     = idx & 7;
    int lane  = (idx >> 3) & 63;
    int ni    = (idx >> 9) & 3;
    int chunk = (idx >> 11) & 31;
    int colblk = idx >> 16;
    int col = colblk * 64 + ni * 16 + (lane & 15);
    int k   = chunk * 32 + (lane >> 4) * 8 + j;
    float v = (k < 768) ? W2[((size_t)(k >> 8) * 256 + (k & 255)) * 256 + col]
                        : root2[(size_t)(k - 768) * 256 + col];
    Wf[idx] = f2b(v);
}

// ---------------- concat MFMA GEMM v5: WAVE-AUTONOMOUS, zero __syncthreads.
// h2[M][256] = relu( [hagg | h1] (M x 1024) @ W2cat + b2 )
// Each wave owns 32 rows x 64 cols (2x4 MFMA grid). B frags load coalesced from
// fragment-ordered Wf (no LDS). A chunks load coalesced (4 lanes x 16B per row),
// round-trip through WAVE-PRIVATE LDS (ds ops need no barrier within a wave) to
// reach MFMA A-layout. 2-deep register prefetch survives across steps because
// there is no s_barrier to force vmcnt(0) drains.
__global__ __launch_bounds__(256) void gemm_cat(const bf16* __restrict__ hagg,
                                                const bf16* __restrict__ h1,
                                                const bf16* __restrict__ Wf,
                                                const float* __restrict__ bias,
                                                bf16* __restrict__ h2) {
    __shared__ short lds[4][32 * 40];   // per-wave A chunk (32 rows x 32 k, stride 40)
    const int t = threadIdx.x;
    const int wave = t >> 6, lane = t & 63;
    const int quad = lane >> 4, l16 = lane & 15;
    const int row0 = blockIdx.y * 64 + (wave & 1) * 32;
    const int colblk = blockIdx.x * 2 + (wave >> 1);    // 0..3 -> 64-col group
    const int rsub = lane >> 2;        // 0..15: row within 16-row half
    const int ksub = (lane & 3) * 8;   // k-element offset within 32-chunk
    short* A = lds[wave];

    const int r0 = min(row0 + rsub, NN - 1);        // clamped (stores guarded)
    const int r1 = min(row0 + 16 + rsub, NN - 1);
    const bf16* gA0 = hagg + (size_t)r0 * 768 + ksub;
    const bf16* gA1 = hagg + (size_t)r1 * 768 + ksub;
    const bf16* gH0 = h1 + (size_t)r0 * 256 + ksub;
    const bf16* gH1 = h1 + (size_t)r1 * 256 + ksub;
    const short8* bbase = (const short8*)Wf + (size_t)colblk * 32 * 4 * 64 + lane;

    auto loadA2 = [&](int k0, short8& a0, short8& a1) {
        if (k0 < 768) { a0 = *(const short8*)(gA0 + k0); a1 = *(const short8*)(gA1 + k0); }
        else          { a0 = *(const short8*)(gH0 + k0 - 768); a1 = *(const short8*)(gH1 + k0 - 768); }
    };
    auto loadB = [&](int chunk, short8* bf4) {
        const short8* bp = bbase + (size_t)chunk * 4 * 64;
#pragma unroll
        for (int ni = 0; ni < 4; ++ni) bf4[ni] = bp[ni * 64];
    };

    floatx4 acc[2][4] = {};
    short8 aC0, aC1, bC[4], aN0, aN1, bN[4];
    loadA2(0, aC0, aC1);
    loadB(0, bC);

    for (int i = 0; i < 32; ++i) {
        *(short8*)&A[rsub * 40 + ksub] = aC0;          // stage chunk i (wave-private)
        *(short8*)&A[(16 + rsub) * 40 + ksub] = aC1;
        if (i + 1 < 32) {                              // prefetch chunk i+1 (global)
            loadA2((i + 1) * 32, aN0, aN1);
            loadB(i + 1, bN);
        }
        short8 af0 = *(const short8*)&A[l16 * 40 + quad * 8];         // lgkmcnt-waited
        short8 af1 = *(const short8*)&A[(16 + l16) * 40 + quad * 8];
#pragma unroll
        for (int ni = 0; ni < 4; ++ni) {
            acc[0][ni] = __builtin_amdgcn_mfma_f32_16x16x32_bf16(af0, bC[ni], acc[0][ni], 0, 0, 0);
            acc[1][ni] = __builtin_amdgcn_mfma_f32_16x16x32_bf16(af1, bC[ni], acc[1][ni], 0, 0, 0);
        }
        aC0 = aN0; aC1 = aN1;
#pragma unroll
        for (int ni = 0; ni < 4; ++ni) bC[ni] = bN[ni];
    }

    // C/D layout: col = lane&15, row = quad*4 + reg   [m89/m91-verified]
#pragma unroll
    for (int mi = 0; mi < 2; ++mi) {
#pragma unroll
        for (int ni = 0; ni < 4; ++ni) {
            int n = colblk * 64 + ni * 16 + l16;
            float bn = bias[n];
#pragma unroll
            for (int ii = 0; ii < 4; ++ii) {
                int gm = row0 + mi * 16 + quad * 4 + ii;
                if (gm < NN) {
                    float v = acc[mi][ni][ii] + bn;
                    h2[(size_t)gm * 256 + n] = f2b(fmaxf(v, 0.f));
                }
            }
        }
    }
}

// ---------------- pooling via run-length reduction (batch is SORTED)
#define PN 64
__global__ __launch_bounds__(256) void pool_rle(const int* __restrict__ batch,
                                                const bf16* __restrict__ H,
                                                float* __restrict__ pool,
                                                float* __restrict__ gcnt) {
    int t = threadIdx.x;               // feature dim
    int n0 = blockIdx.x * PN;
    int nend = n0 + PN; if (nend > NN) nend = NN;
    int curg = batch[n0];
    float acc = 0.f, cnt = 0.f;
    for (int n = n0; n < nend; ++n) {
        int g = batch[n];              // wave-uniform
        if (g != curg) {
            atomicAdd(&pool[(size_t)curg * 256 + t], acc);
            if (t == 0) atomicAdd(&gcnt[curg], cnt);
            acc = 0.f; cnt = 0.f; curg = g;
        }
        acc += b2f(H[(size_t)n * 256 + t]);
        cnt += 1.f;
    }
    atomicAdd(&pool[(size_t)curg * 256 + t], acc);
    if (t == 0) atomicAdd(&gcnt[curg], cnt);
}

// ---------------- head: out[g][c] = (pool[g]/cnt[g]) @ lin_w + lin_b  (f32 out)
__global__ __launch_bounds__(256) void final_head(const float* __restrict__ pool,
                                                  const float* __restrict__ gcnt,
                                                  const float* __restrict__ lin_w,
                                                  const float* __restrict__ lin_b,
                                                  float* __restrict__ out) {
    __shared__ float sm[256];
    int g = blockIdx.x, t = threadIdx.x;
    float inv = 1.0f / fmaxf(gcnt[g], 1.0f);
    sm[t] = pool[(size_t)g * 256 + t] * inv;
    __syncthreads();
    if (t < NCLS) {
        float s = lin_b[t];
        for (int d = 0; d < 256; ++d) s += sm[d] * lin_w[d * NCLS + t];
        out[g * NCLS + t] = s;
    }
}

extern "C" void kernel_launch(void* const* d_in, const int* in_sizes, int n_in,
                              void* d_out, int out_size, void* d_ws, size_t ws_size,
                              hipStream_t stream) {
    const int*   s_idx = (const int*)d_in[0];
    const int*   c_idx = (const int*)d_in[1];
    const int*   p_idx = (const int*)d_in[2];
    const int*   ei    = (const int*)d_in[3];   // (2, NE)
    const int*   et    = (const int*)d_in[4];
    const int*   batch = (const int*)d_in[5];
    const float* se    = (const float*)d_in[6];
    const float* ce    = (const float*)d_in[7];
    const float* pe    = (const float*)d_in[8];
    const float* W1    = (const float*)d_in[9];   // (3, 384, 256)
    const float* root1 = (const float*)d_in[10];  // (384, 256)
    const float* b1    = (const float*)d_in[11];
    const float* W2    = (const float*)d_in[12];  // (3, 256, 256)
    const float* root2 = (const float*)d_in[13];  // (256, 256)
    const float* b2    = (const float*)d_in[14];
    const float* lin_w = (const float*)d_in[15];
    const float* lin_b = (const float*)d_in[16];
    float* out = (float*)d_out;

    // ---- workspace carve-up (~175 MB; ws_size >= 190 MB confirmed in round 6)
    char* w = (char*)d_ws;
    size_t o = 0;
    auto alloc = [&](size_t bytes) -> void* {
        o = (o + 15) & ~(size_t)15;
        void* ptr = w + o;
        o += bytes;
        return ptr;
    };
    bf16*  hagg   = (bf16*) alloc((size_t)NN * 768 * 2);   // 76.8 MB
    bf16*  h1     = (bf16*) alloc((size_t)NN * 256 * 2);
    bf16*  h2     = (bf16*) alloc((size_t)NN * 256 * 2);
    bf16*  comb   = (bf16*) alloc((size_t)4 * NCMB * 256 * 2);
    int*   combo  = (int*)  alloc((size_t)NN * 4);
    int*   eidx   = (int*)  alloc((size_t)NE * 4);
    int*   ecmb   = (int*)  alloc((size_t)NE * 4);
    int*   cnt    = (int*)  alloc((size_t)NB * 4);
    int*   off    = (int*)  alloc((size_t)(NB + 1) * 4);
    int*   cursor = (int*)  alloc((size_t)NB * 4);
    int*   bsum   = (int*)  alloc((size_t)NBLK * 4);
    int*   bbase  = (int*)  alloc((size_t)NBLK * 4);
    float* tab    = (float*)alloc((size_t)4 * 144 * 256 * 4);
    bf16*  Wf     = (bf16*) alloc((size_t)256 * 1024 * 2);
    float* pool   = (float*)alloc((size_t)NG * 256 * 4);
    float* gcnt   = (float*)alloc((size_t)NG * 4);
    (void)ws_size;

    // ---- CSR build (node_combo first: scatter_edges materializes ecmb)
    node_combo<<<(NN + 255) / 256, 256, 0, stream>>>(s_idx, c_idx, p_idx, combo);
    zero_u32<<<(NB + 255) / 256, 256, 0, stream>>>((unsigned*)cnt, NB);
    count_edges<<<(NE + 255) / 256, 256, 0, stream>>>(ei, et, cnt);
    scan_block_sums<<<NBLK, 256, 0, stream>>>(cnt, bsum);
    scan_base<<<1, 64, 0, stream>>>(bsum, bbase, off);
    scan_write<<<NBLK, 256, 0, stream>>>(cnt, bbase, off, cursor);
    scatter_edges<<<(NE + 255) / 256, 256, 0, stream>>>(ei, et, combo, cursor, eidx, ecmb);

    // ---- weight/table prep
    tab_gemm<<<4 * 144, 256, 0, stream>>>(se, ce, pe, W1, root1, tab);
    comb_build<<<4 * NCMB, 256, 0, stream>>>(tab, b1, comb);
    conv_w2cat<<<(256 * 1024 + 255) / 256, 256, 0, stream>>>(W2, root2, Wf);

    // ---- layer 1: fully fused combo-table gather
    l1_fused<<<(NN + 3) / 4, 256, 0, stream>>>(off, ecmb, combo, comb, h1);

    // ---- layer 2: aggregate-first, then one wave-autonomous concat GEMM
    agg_all<<<(NN + 3) / 4, 256, 0, stream>>>(off, eidx, h1, hagg);
    dim3 g2(2, (NN + 63) / 64);
    gemm_cat<<<g2, 256, 0, stream>>>(hagg, h1, Wf, b2, h2);

    // ---- pool + head
    zero_u32<<<(NG * 256 + NG + 255) / 256, 256, 0, stream>>>((unsigned*)pool, NG * 256 + NG);
    pool_rle<<<(NN + PN - 1) / PN, 256, 0, stream>>>(batch, h2, pool, gcnt);
    final_head<<<NG, 256, 0, stream>>>(pool, gcnt, lin_w, lin_b, out);
}

// Round 12
// 424.608 us; speedup vs baseline: 1.2606x; 1.0243x over previous
//
#include <hip/hip_runtime.h>
#include <hip/hip_bf16.h>

#define NN 50000          // nodes
#define NE 800000         // edges
#define NR 3              // relations
#define NG 500            // graphs
#define NB (NN * NR)      // (dst, rel) buckets = 150000
#define NCLS 10
#define NCMB 8192         // 8 shapes * 8 colors * 128 positions
#define CHUNK 2048        // scan elements per block
#define NBLK ((NB + CHUNK - 1) / CHUNK)   // 74

// prep1 role block ranges
#define P1_COMBO   196                        // node_combo: 50000/256
#define P1_ZCNT    586                        // zero cnt: 150000/256
#define P1_ZPOOL   502                        // zero pool+gcnt: 128500/256
#define P1_TAB     576                        // tab_gemm: 4*144
#define P1_WF      1024                       // conv_w2cat: 256*1024/256
#define P1_TOTAL   (P1_COMBO + P1_ZCNT + P1_ZPOOL + P1_TAB + P1_WF)   // 2884
// prep2 role block ranges
#define P2_CNT     3125                       // count_edges: NE/256
#define P2_COMB    (4 * NCMB)                 // comb_build
#define P2_TOTAL   (P2_CNT + P2_COMB)         // 35893

typedef __hip_bfloat16 bf16;
typedef __attribute__((ext_vector_type(8))) short short8;   // bf16x8 MFMA frag
typedef __attribute__((ext_vector_type(4))) float floatx4;  // MFMA accumulator

static __device__ __forceinline__ float b2f(bf16 x) { return __bfloat162float(x); }
static __device__ __forceinline__ bf16  f2b(float x) { return __float2bfloat16(x); }
static __device__ __forceinline__ float bs2f(short x) {
    return __bfloat162float(*reinterpret_cast<const bf16*>(&x));
}
static __device__ __forceinline__ short f2bs(float x) {
    bf16 b = __float2bfloat16(x);
    return *reinterpret_cast<const short*>(&b);
}

// ---------------- prep1: all independent prep work, role-dispatched by blockIdx
// [0,196) node_combo | [196,782) zero cnt | [782,1284) zero pool+gcnt |
// [1284,1860) tab_gemm | [1860,2884) conv_w2cat (fragment-ordered Wf)
__global__ __launch_bounds__(256) void prep1(const int* __restrict__ s,
                                             const int* __restrict__ c,
                                             const int* __restrict__ p,
                                             const float* __restrict__ se,
                                             const float* __restrict__ ce,
                                             const float* __restrict__ pe,
                                             const float* __restrict__ W1,
                                             const float* __restrict__ root1,
                                             const float* __restrict__ W2,
                                             const float* __restrict__ root2,
                                             int* __restrict__ combo,
                                             unsigned* __restrict__ cnt,
                                             unsigned* __restrict__ poolz,
                                             float* __restrict__ tab,
                                             bf16* __restrict__ Wf) {
    int b = blockIdx.x, t = threadIdx.x;
    if (b < P1_COMBO) {
        int n = b * 256 + t;
        if (n < NN) combo[n] = (s[n] << 10) | (c[n] << 7) | p[n];
        return;
    }
    b -= P1_COMBO;
    if (b < P1_ZCNT) {
        int i = b * 256 + t;
        if (i < NB) cnt[i] = 0u;
        return;
    }
    b -= P1_ZCNT;
    if (b < P1_ZPOOL) {
        int i = b * 256 + t;
        if (i < NG * 256 + NG) poolz[i] = 0u;
        return;
    }
    b -= P1_ZPOOL;
    if (b < P1_TAB) {
        // tab[r][row][n]: rows 0..7 = se@Wseg0, 8..15 = ce@Wseg1, 16..143 = pe@Wseg2
        int r = b / 144, row = b % 144;
        const float* A; int segk;
        if (row < 8)       { A = se + row * 128;        segk = 0; }
        else if (row < 16) { A = ce + (row - 8) * 128;  segk = 128; }
        else               { A = pe + (row - 16) * 128; segk = 256; }
        const float* W = (r < 3) ? (W1 + (size_t)r * 384 * 256) : root1;
        float acc = 0.f;
        for (int k = 0; k < 128; ++k)
            acc += A[k] * W[(size_t)(segk + k) * 256 + t];
        tab[((size_t)r * 144 + row) * 256 + t] = acc;
        return;
    }
    b -= P1_TAB;
    {   // conv_w2cat: Wf in MFMA-fragment order (wave B-frag = contiguous 1 KB)
        int idx = b * 256 + t;
        int j     = idx & 7;
        int lane  = (idx >> 3) & 63;
        int ni    = (idx >> 9) & 3;
        int chunk = (idx >> 11) & 31;
        int colblk = idx >> 16;
        int col = colblk * 64 + ni * 16 + (lane & 15);
        int k   = chunk * 32 + (lane >> 4) * 8 + j;
        float v = (k < 768) ? W2[((size_t)(k >> 8) * 256 + (k & 255)) * 256 + col]
                            : root2[(size_t)(k - 768) * 256 + col];
        Wf[idx] = f2b(v);
    }
}

// ---------------- prep2: count_edges + comb_build (both depend only on prep1)
__global__ __launch_bounds__(256) void prep2(const int* __restrict__ ei,
                                             const int* __restrict__ et,
                                             int* __restrict__ cnt,
                                             const float* __restrict__ tab,
                                             const float* __restrict__ b1,
                                             bf16* __restrict__ comb) {
    int b = blockIdx.x, t = threadIdx.x;
    if (b < P2_CNT) {
        int e = b * 256 + t;
        if (e < NE) atomicAdd(&cnt[ei[NE + e] * NR + et[e]], 1);
        return;
    }
    b -= P2_CNT;
    {   // comb[r][cmb][d] = tab[r][s]+tab[r][8+c]+tab[r][16+p] (+b1 for r=3)
        int r = b >> 13, cmb = b & (NCMB - 1);
        int si = cmb >> 10, ci = (cmb >> 7) & 7, pi = cmb & 127;
        const float* tr = tab + (size_t)r * 144 * 256;
        float v = tr[si * 256 + t] + tr[(8 + ci) * 256 + t] + tr[(16 + pi) * 256 + t];
        if (r == 3) v += b1[t];
        comb[(size_t)b * 256 + t] = f2b(v);
    }
}

// ---------------- counting-sort scan, phase A: per-block (2048-elem) totals
__global__ __launch_bounds__(256) void scan_block_sums(const int* __restrict__ cnt,
                                                       int* __restrict__ bsum) {
    __shared__ int sm[256];
    int b = blockIdx.x, t = threadIdx.x;
    int base = b * CHUNK + t * 8, s = 0;
#pragma unroll
    for (int j = 0; j < 8; ++j) { int i = base + j; if (i < NB) s += cnt[i]; }
    sm[t] = s; __syncthreads();
    for (int st = 128; st; st >>= 1) { if (t < st) sm[t] += sm[t + st]; __syncthreads(); }
    if (!t) bsum[b] = sm[0];
}

// ---------------- phase B+C merged: inline cross-block base + in-block scan
__global__ __launch_bounds__(256) void scan_write(const int* __restrict__ cnt,
                                                  const int* __restrict__ bsum,
                                                  int* __restrict__ off,
                                                  int* __restrict__ cursor) {
    int b = blockIdx.x, t = threadIdx.x;
    int bbase = 0;                              // wave-uniform 74-iteration prefix
    for (int i = 0; i < b; ++i) bbase += bsum[i];
    if (b == 0 && t == 0) {
        int tot = 0;
        for (int i = 0; i < NBLK; ++i) tot += bsum[i];
        off[NB] = tot;                          // == NE
    }
    int base = b * CHUNK + t * 8;
    int v[8], ts = 0;
#pragma unroll
    for (int j = 0; j < 8; ++j) { int i = base + j; v[j] = (i < NB) ? cnt[i] : 0; ts += v[j]; }
    int lane = t & 63, wv = t >> 6;
    int incl = ts;
    for (int d = 1; d < 64; d <<= 1) {
        int o = __shfl_up(incl, d, 64);
        if (lane >= d) incl += o;
    }
    __shared__ int wsum[4];
    if (lane == 63) wsum[wv] = incl;
    __syncthreads();
    int wbase = 0;
    for (int w = 0; w < wv; ++w) wbase += wsum[w];
    int run = bbase + wbase + incl - ts;
#pragma unroll
    for (int j = 0; j < 8; ++j) {
        int i = base + j;
        if (i < NB) { off[i] = run; cursor[i] = run; }
        run += v[j];
    }
}

// ---------------- bucket-sort edges: stores src AND combo[src]
__global__ __launch_bounds__(256) void scatter_edges(const int* __restrict__ ei,
                                                     const int* __restrict__ et,
                                                     const int* __restrict__ combo,
                                                     int* __restrict__ cursor,
                                                     int* __restrict__ eidx,
                                                     int* __restrict__ ecmb) {
    int e = blockIdx.x * 256 + threadIdx.x;
    if (e >= NE) return;
    int b = ei[NE + e] * NR + et[e];
    int pos = atomicAdd(&cursor[b], 1);
    int s = ei[e];
    eidx[pos] = s;
    ecmb[pos] = combo[s];
}

// ---------------- fused layer 1: 4 waves/block, 1 wave/dst, lane-split 8-deep gather
__global__ __launch_bounds__(256) void l1_fused(const int* __restrict__ off,
                                                const int* __restrict__ ecmb,
                                                const int* __restrict__ combo,
                                                const bf16* __restrict__ comb,
                                                bf16* __restrict__ h1) {
    int wave = threadIdx.x >> 6, lane = threadIdx.x & 63;
    int dst = blockIdx.x * 4 + wave;
    if (dst >= NN) return;
    int half = lane >> 5, li8 = (lane & 31) * 8;
    float acc[8];
    if (half == 0) {   // root slice (b1 pre-folded); only half0's acc is used
        int cmbD = combo[dst];
        short8 rv = *(const short8*)(comb + ((size_t)(3 * NCMB) + cmbD) * 256 + li8);
#pragma unroll
        for (int i = 0; i < 8; ++i) acc[i] = bs2f(rv[i]);
    } else {
#pragma unroll
        for (int i = 0; i < 8; ++i) acc[i] = 0.f;
    }
    for (int r = 0; r < NR; ++r) {
        int lo = off[dst * NR + r], hi = off[dst * NR + r + 1];
        if (hi <= lo) continue;                 // empty bucket contributes 0 (matches ref)
        const bf16* cr = comb + (size_t)r * NCMB * 256;
        float s[8] = {};
        int j = lo;
        for (; j + 8 <= hi; j += 8) {           // 4 rows/half in flight
            int c0 = ecmb[j + half],     c1 = ecmb[j + 2 + half];
            int c2 = ecmb[j + 4 + half], c3 = ecmb[j + 6 + half];
            short8 v0 = *(const short8*)(cr + (size_t)c0 * 256 + li8);
            short8 v1 = *(const short8*)(cr + (size_t)c1 * 256 + li8);
            short8 v2 = *(const short8*)(cr + (size_t)c2 * 256 + li8);
            short8 v3 = *(const short8*)(cr + (size_t)c3 * 256 + li8);
#pragma unroll
            for (int i = 0; i < 8; ++i)
                s[i] += (bs2f(v0[i]) + bs2f(v1[i])) + (bs2f(v2[i]) + bs2f(v3[i]));
        }
        for (; j + 2 <= hi; j += 2) {
            int c0 = ecmb[j + half];
            short8 v0 = *(const short8*)(cr + (size_t)c0 * 256 + li8);
#pragma unroll
            for (int i = 0; i < 8; ++i) s[i] += bs2f(v0[i]);
        }
        if (j < hi && half == 0) {              // odd remainder
            short8 v0 = *(const short8*)(cr + (size_t)ecmb[j] * 256 + li8);
#pragma unroll
            for (int i = 0; i < 8; ++i) s[i] += bs2f(v0[i]);
        }
        float inv = 1.0f / (float)(hi - lo);
#pragma unroll
        for (int i = 0; i < 8; ++i) {
            float tot = s[i] + __shfl_xor(s[i], 32);
            if (half == 0) acc[i] += tot * inv;
        }
    }
    if (half == 0) {
        short8 o;
#pragma unroll
        for (int i = 0; i < 8; ++i) o[i] = f2bs(fmaxf(acc[i], 0.f));
        *(short8*)(h1 + (size_t)dst * 256 + li8) = o;
    }
}

// ---------------- per-relation mean aggregation of h1:
// hagg[dst][r*256+d] = mean_{src in bucket(dst,r)} h1[src][d]   (0 if empty)
__global__ __launch_bounds__(256) void agg_all(const int* __restrict__ off,
                                               const int* __restrict__ eidx,
                                               const bf16* __restrict__ h1,
                                               bf16* __restrict__ hagg) {
    int wave = threadIdx.x >> 6, lane = threadIdx.x & 63;
    int dst = blockIdx.x * 4 + wave;
    if (dst >= NN) return;
    int half = lane >> 5, li8 = (lane & 31) * 8;
    for (int r = 0; r < NR; ++r) {
        int lo = off[dst * NR + r], hi = off[dst * NR + r + 1];
        float s[8] = {};
        int j = lo;
        for (; j + 8 <= hi; j += 8) {           // 4 rows/half in flight
            int e0 = eidx[j + half],     e1 = eidx[j + 2 + half];
            int e2 = eidx[j + 4 + half], e3 = eidx[j + 6 + half];
            short8 v0 = *(const short8*)(h1 + (size_t)e0 * 256 + li8);
            short8 v1 = *(const short8*)(h1 + (size_t)e1 * 256 + li8);
            short8 v2 = *(const short8*)(h1 + (size_t)e2 * 256 + li8);
            short8 v3 = *(const short8*)(h1 + (size_t)e3 * 256 + li8);
#pragma unroll
            for (int i = 0; i < 8; ++i)
                s[i] += (bs2f(v0[i]) + bs2f(v1[i])) + (bs2f(v2[i]) + bs2f(v3[i]));
        }
        for (; j + 2 <= hi; j += 2) {
            int e0 = eidx[j + half];
            short8 v0 = *(const short8*)(h1 + (size_t)e0 * 256 + li8);
#pragma unroll
            for (int i = 0; i < 8; ++i) s[i] += bs2f(v0[i]);
        }
        if (j < hi && half == 0) {
            short8 v0 = *(const short8*)(h1 + (size_t)eidx[j] * 256 + li8);
#pragma unroll
            for (int i = 0; i < 8; ++i) s[i] += bs2f(v0[i]);
        }
        float inv = (hi > lo) ? 1.0f / (float)(hi - lo) : 0.f;
        short8 o;
#pragma unroll
        for (int i = 0; i < 8; ++i) {
            float tot = s[i] + __shfl_xor(s[i], 32);
            o[i] = f2bs(tot * inv);
        }
        if (half == 0)
            *(short8*)(hagg + (size_t)dst * 768 + r * 256 + li8) = o;
    }
}

// ---------------- concat MFMA GEMM v6: wave-autonomous (no __syncthreads) +
// ping-pong register sets (zero cross-step v_mov copies) + LDS parity buffers.
// h2[M][256] = relu( [hagg | h1] (M x 1024) @ W2cat + b2 )
__global__ __launch_bounds__(256) void gemm_cat(const bf16* __restrict__ hagg,
                                                const bf16* __restrict__ h1,
                                                const bf16* __restrict__ Wf,
                                                const float* __restrict__ bias,
                                                bf16* __restrict__ h2) {
    __shared__ short lds[4][2][32 * 40];    // per-wave, parity-double-buffered A chunk
    const int t = threadIdx.x;
    const int wave = t >> 6, lane = t & 63;
    const int quad = lane >> 4, l16 = lane & 15;
    const int row0 = blockIdx.y * 64 + (wave & 1) * 32;
    const int colblk = blockIdx.x * 2 + (wave >> 1);    // 0..3 -> 64-col group
    const int rsub = lane >> 2;        // 0..15: row within 16-row half
    const int ksub = (lane & 3) * 8;   // k-element offset within 32-chunk
    short* A0 = lds[wave][0];
    short* A1 = lds[wave][1];

    const int r0 = min(row0 + rsub, NN - 1);        // clamped (stores guarded)
    const int r1 = min(row0 + 16 + rsub, NN - 1);
    const bf16* gA0 = hagg + (size_t)r0 * 768 + ksub;
    const bf16* gA1 = hagg + (size_t)r1 * 768 + ksub;
    const bf16* gH0 = h1 + (size_t)r0 * 256 + ksub;
    const bf16* gH1 = h1 + (size_t)r1 * 256 + ksub;
    const short8* bbase = (const short8*)Wf + (size_t)colblk * 32 * 4 * 64 + lane;

    auto loadA2 = [&](int k0, short8& a0, short8& a1) {
        if (k0 < 768) { a0 = *(const short8*)(gA0 + k0); a1 = *(const short8*)(gA1 + k0); }
        else          { a0 = *(const short8*)(gH0 + k0 - 768); a1 = *(const short8*)(gH1 + k0 - 768); }
    };
    auto loadB = [&](int chunk, short8* bf4) {
        const short8* bp = bbase + (size_t)chunk * 4 * 64;
#pragma unroll
        for (int ni = 0; ni < 4; ++ni) bf4[ni] = bp[ni * 64];
    };

    floatx4 acc[2][4] = {};
    short8 aE0, aE1, bE[4];     // even-chunk register set
    short8 aO0, aO1, bO[4];     // odd-chunk register set
    loadA2(0, aE0, aE1);  loadB(0, bE);
    loadA2(32, aO0, aO1); loadB(1, bO);

#pragma unroll
    for (int i = 0; i < 32; i += 2) {
        // ---- even chunk i: parity buffer 0, set E
        *(short8*)&A0[rsub * 40 + ksub] = aE0;
        *(short8*)&A0[(16 + rsub) * 40 + ksub] = aE1;
        {
            short8 af0 = *(const short8*)&A0[l16 * 40 + quad * 8];
            short8 af1 = *(const short8*)&A0[(16 + l16) * 40 + quad * 8];
#pragma unroll
            for (int ni = 0; ni < 4; ++ni) {
                acc[0][ni] = __builtin_amdgcn_mfma_f32_16x16x32_bf16(af0, bE[ni], acc[0][ni], 0, 0, 0);
                acc[1][ni] = __builtin_amdgcn_mfma_f32_16x16x32_bf16(af1, bE[ni], acc[1][ni], 0, 0, 0);
            }
        }
        if (i + 2 < 32) { loadA2((i + 2) * 32, aE0, aE1); loadB(i + 2, bE); }
        // ---- odd chunk i+1: parity buffer 1, set O
        *(short8*)&A1[rsub * 40 + ksub] = aO0;
        *(short8*)&A1[(16 + rsub) * 40 + ksub] = aO1;
        {
            short8 af0 = *(const short8*)&A1[l16 * 40 + quad * 8];
            short8 af1 = *(const short8*)&A1[(16 + l16) * 40 + quad * 8];
#pragma unroll
            for (int ni = 0; ni < 4; ++ni) {
                acc[0][ni] = __builtin_amdgcn_mfma_f32_16x16x32_bf16(af0, bO[ni], acc[0][ni], 0, 0, 0);
                acc[1][ni] = __builtin_amdgcn_mfma_f32_16x16x32_bf16(af1, bO[ni], acc[1][ni], 0, 0, 0);
            }
        }
        if (i + 3 < 32) { loadA2((i + 3) * 32, aO0, aO1); loadB(i + 3, bO); }
    }

    // C/D layout: col = lane&15, row = quad*4 + reg   [m89/m91-verified]
#pragma unroll
    for (int mi = 0; mi < 2; ++mi) {
#pragma unroll
        for (int ni = 0; ni < 4; ++ni) {
            int n = colblk * 64 + ni * 16 + l16;
            float bn = bias[n];
#pragma unroll
            for (int ii = 0; ii < 4; ++ii) {
                int gm = row0 + mi * 16 + quad * 4 + ii;
                if (gm < NN) {
                    float v = acc[mi][ni][ii] + bn;
                    h2[(size_t)gm * 256 + n] = f2b(fmaxf(v, 0.f));
                }
            }
        }
    }
}

// ---------------- pooling via run-length reduction (batch is SORTED)
#define PN 64
__global__ __launch_bounds__(256) void pool_rle(const int* __restrict__ batch,
                                                const bf16* __restrict__ H,
                                                float* __restrict__ pool,
                                                float* __restrict__ gcnt) {
    int t = threadIdx.x;               // feature dim
    int n0 = blockIdx.x * PN;
    int nend = n0 + PN; if (nend > NN) nend = NN;
    int curg = batch[n0];
    float acc = 0.f, cnt = 0.f;
    for (int n = n0; n < nend; ++n) {
        int g = batch[n];              // wave-uniform
        if (g != curg) {
            atomicAdd(&pool[(size_t)curg * 256 + t], acc);
            if (t == 0) atomicAdd(&gcnt[curg], cnt);
            acc = 0.f; cnt = 0.f; curg = g;
        }
        acc += b2f(H[(size_t)n * 256 + t]);
        cnt += 1.f;
    }
    atomicAdd(&pool[(size_t)curg * 256 + t], acc);
    if (t == 0) atomicAdd(&gcnt[curg], cnt);
}

// ---------------- head: out[g][c] = (pool[g]/cnt[g]) @ lin_w + lin_b  (f32 out)
__global__ __launch_bounds__(256) void final_head(const float* __restrict__ pool,
                                                  const float* __restrict__ gcnt,
                                                  const float* __restrict__ lin_w,
                                                  const float* __restrict__ lin_b,
                                                  float* __restrict__ out) {
    __shared__ float sm[256];
    int g = blockIdx.x, t = threadIdx.x;
    float inv = 1.0f / fmaxf(gcnt[g], 1.0f);
    sm[t] = pool[(size_t)g * 256 + t] * inv;
    __syncthreads();
    if (t < NCLS) {
        float s = lin_b[t];
        for (int d = 0; d < 256; ++d) s += sm[d] * lin_w[d * NCLS + t];
        out[g * NCLS + t] = s;
    }
}

extern "C" void kernel_launch(void* const* d_in, const int* in_sizes, int n_in,
                              void* d_out, int out_size, void* d_ws, size_t ws_size,
                              hipStream_t stream) {
    const int*   s_idx = (const int*)d_in[0];
    const int*   c_idx = (const int*)d_in[1];
    const int*   p_idx = (const int*)d_in[2];
    const int*   ei    = (const int*)d_in[3];   // (2, NE)
    const int*   et    = (const int*)d_in[4];
    const int*   batch = (const int*)d_in[5];
    const float* se    = (const float*)d_in[6];
    const float* ce    = (const float*)d_in[7];
    const float* pe    = (const float*)d_in[8];
    const float* W1    = (const float*)d_in[9];   // (3, 384, 256)
    const float* root1 = (const float*)d_in[10];  // (384, 256)
    const float* b1    = (const float*)d_in[11];
    const float* W2    = (const float*)d_in[12];  // (3, 256, 256)
    const float* root2 = (const float*)d_in[13];  // (256, 256)
    const float* b2    = (const float*)d_in[14];
    const float* lin_w = (const float*)d_in[15];
    const float* lin_b = (const float*)d_in[16];
    float* out = (float*)d_out;

    // ---- workspace carve-up (~175 MB; ws_size >= 190 MB confirmed in round 6)
    char* w = (char*)d_ws;
    size_t o = 0;
    auto alloc = [&](size_t bytes) -> void* {
        o = (o + 15) & ~(size_t)15;
        void* ptr = w + o;
        o += bytes;
        return ptr;
    };
    bf16*  hagg   = (bf16*) alloc((size_t)NN * 768 * 2);   // 76.8 MB
    bf16*  h1     = (bf16*) alloc((size_t)NN * 256 * 2);
    bf16*  h2     = (bf16*) alloc((size_t)NN * 256 * 2);
    bf16*  comb   = (bf16*) alloc((size_t)4 * NCMB * 256 * 2);
    int*   combo  = (int*)  alloc((size_t)NN * 4);
    int*   eidx   = (int*)  alloc((size_t)NE * 4);
    int*   ecmb   = (int*)  alloc((size_t)NE * 4);
    int*   cnt    = (int*)  alloc((size_t)NB * 4);
    int*   off    = (int*)  alloc((size_t)(NB + 1) * 4);
    int*   cursor = (int*)  alloc((size_t)NB * 4);
    int*   bsum   = (int*)  alloc((size_t)NBLK * 4);
    float* tab    = (float*)alloc((size_t)4 * 144 * 256 * 4);
    bf16*  Wf     = (bf16*) alloc((size_t)256 * 1024 * 2);
    float* pool   = (float*)alloc((size_t)NG * 256 * 4);   // pool + gcnt contiguous
    float* gcnt   = (float*)alloc((size_t)NG * 4);
    (void)ws_size;

    // ---- 1. all independent prep (combo ids, zeros, layer-1 tab GEMM, Wf shuffle)
    prep1<<<P1_TOTAL, 256, 0, stream>>>(s_idx, c_idx, p_idx, se, ce, pe,
                                        W1, root1, W2, root2,
                                        combo, (unsigned*)cnt, (unsigned*)pool, tab, Wf);
    // ---- 2. edge counts + combo-table build
    prep2<<<P2_TOTAL, 256, 0, stream>>>(ei, et, cnt, tab, b1, comb);
    // ---- 3-5. CSR: scan + scatter
    scan_block_sums<<<NBLK, 256, 0, stream>>>(cnt, bsum);
    scan_write<<<NBLK, 256, 0, stream>>>(cnt, bsum, off, cursor);
    scatter_edges<<<(NE + 255) / 256, 256, 0, stream>>>(ei, et, combo, cursor, eidx, ecmb);
    // ---- 6. layer 1: fully fused combo-table gather
    l1_fused<<<(NN + 3) / 4, 256, 0, stream>>>(off, ecmb, combo, comb, h1);
    // ---- 7-8. layer 2: aggregate-first, then one wave-autonomous concat GEMM
    agg_all<<<(NN + 3) / 4, 256, 0, stream>>>(off, eidx, h1, hagg);
    dim3 g2(2, (NN + 63) / 64);
    gemm_cat<<<g2, 256, 0, stream>>>(hagg, h1, Wf, b2, h2);
    // ---- 9-10. pool + head
    pool_rle<<<(NN + PN - 1) / PN, 256, 0, stream>>>(batch, h2, pool, gcnt);
    final_head<<<NG, 256, 0, stream>>>(pool, gcnt, lin_w, lin_b, out);
}

// Round 13
// 411.931 us; speedup vs baseline: 1.2994x; 1.0308x over previous
//
#include <hip/hip_runtime.h>
#include <hip/hip_bf16.h>

#define NN 50000          // nodes
#define NE 800000         // edges
#define NR 3              // relations
#define NG 500            // graphs
#define NB (NN * NR)      // (dst, rel) buckets = 150000
#define NCLS 10
#define NCMB 8192         // 8 shapes * 8 colors * 128 positions
#define CHUNK 2048        // scan elements per block
#define NBLK ((NB + CHUNK - 1) / CHUNK)   // 74

// prep1 role block ranges
#define P1_COMBO   196                        // node_combo: 50000/256
#define P1_ZCNT    586                        // zero cnt: 150000/256
#define P1_ZPOOL   502                        // zero pool+gcnt: 128500/256
#define P1_TAB     576                        // tab_gemm: 4*144
#define P1_WF      1024                       // conv_w2cat: 256*1024/256
#define P1_TOTAL   (P1_COMBO + P1_ZCNT + P1_ZPOOL + P1_TAB + P1_WF)   // 2884
// prep2 role block ranges
#define P2_CNT     3125                       // count_edges: NE/256
#define P2_COMB    (4 * NCMB)                 // comb_build
#define P2_TOTAL   (P2_CNT + P2_COMB)         // 35893

typedef __hip_bfloat16 bf16;
typedef __attribute__((ext_vector_type(8))) short short8;   // bf16x8 MFMA frag
typedef __attribute__((ext_vector_type(4))) float floatx4;  // MFMA accumulator

static __device__ __forceinline__ float b2f(bf16 x) { return __bfloat162float(x); }
static __device__ __forceinline__ bf16  f2b(float x) { return __float2bfloat16(x); }
static __device__ __forceinline__ float bs2f(short x) {
    return __bfloat162float(*reinterpret_cast<const bf16*>(&x));
}
static __device__ __forceinline__ short f2bs(float x) {
    bf16 b = __float2bfloat16(x);
    return *reinterpret_cast<const short*>(&b);
}

// ---------------- prep1: all independent prep work, role-dispatched by blockIdx
__global__ __launch_bounds__(256) void prep1(const int* __restrict__ s,
                                             const int* __restrict__ c,
                                             const int* __restrict__ p,
                                             const float* __restrict__ se,
                                             const float* __restrict__ ce,
                                             const float* __restrict__ pe,
                                             const float* __restrict__ W1,
                                             const float* __restrict__ root1,
                                             const float* __restrict__ W2,
                                             const float* __restrict__ root2,
                                             int* __restrict__ combo,
                                             unsigned* __restrict__ cnt,
                                             unsigned* __restrict__ poolz,
                                             float* __restrict__ tab,
                                             bf16* __restrict__ Wf) {
    int b = blockIdx.x, t = threadIdx.x;
    if (b < P1_COMBO) {
        int n = b * 256 + t;
        if (n < NN) combo[n] = (s[n] << 10) | (c[n] << 7) | p[n];
        return;
    }
    b -= P1_COMBO;
    if (b < P1_ZCNT) {
        int i = b * 256 + t;
        if (i < NB) cnt[i] = 0u;
        return;
    }
    b -= P1_ZCNT;
    if (b < P1_ZPOOL) {
        int i = b * 256 + t;
        if (i < NG * 256 + NG) poolz[i] = 0u;
        return;
    }
    b -= P1_ZPOOL;
    if (b < P1_TAB) {
        // tab[r][row][n]: rows 0..7 = se@Wseg0, 8..15 = ce@Wseg1, 16..143 = pe@Wseg2
        int r = b / 144, row = b % 144;
        const float* A; int segk;
        if (row < 8)       { A = se + row * 128;        segk = 0; }
        else if (row < 16) { A = ce + (row - 8) * 128;  segk = 128; }
        else               { A = pe + (row - 16) * 128; segk = 256; }
        const float* W = (r < 3) ? (W1 + (size_t)r * 384 * 256) : root1;
        float acc = 0.f;
        for (int k = 0; k < 128; ++k)
            acc += A[k] * W[(size_t)(segk + k) * 256 + t];
        tab[((size_t)r * 144 + row) * 256 + t] = acc;
        return;
    }
    b -= P1_TAB;
    {   // conv_w2cat: Wf in MFMA-fragment order (wave B-frag = contiguous 1 KB)
        int idx = b * 256 + t;
        int j     = idx & 7;
        int lane  = (idx >> 3) & 63;
        int ni    = (idx >> 9) & 3;
        int chunk = (idx >> 11) & 31;
        int colblk = idx >> 16;
        int col = colblk * 64 + ni * 16 + (lane & 15);
        int k   = chunk * 32 + (lane >> 4) * 8 + j;
        float v = (k < 768) ? W2[((size_t)(k >> 8) * 256 + (k & 255)) * 256 + col]
                            : root2[(size_t)(k - 768) * 256 + col];
        Wf[idx] = f2b(v);
    }
}

// ---------------- prep2: count_edges + comb_build
__global__ __launch_bounds__(256) void prep2(const int* __restrict__ ei,
                                             const int* __restrict__ et,
                                             int* __restrict__ cnt,
                                             const float* __restrict__ tab,
                                             const float* __restrict__ b1,
                                             bf16* __restrict__ comb) {
    int b = blockIdx.x, t = threadIdx.x;
    if (b < P2_CNT) {
        int e = b * 256 + t;
        if (e < NE) atomicAdd(&cnt[ei[NE + e] * NR + et[e]], 1);
        return;
    }
    b -= P2_CNT;
    {   // comb[r][cmb][d] = tab[r][s]+tab[r][8+c]+tab[r][16+p] (+b1 for r=3)
        int r = b >> 13, cmb = b & (NCMB - 1);
        int si = cmb >> 10, ci = (cmb >> 7) & 7, pi = cmb & 127;
        const float* tr = tab + (size_t)r * 144 * 256;
        float v = tr[si * 256 + t] + tr[(8 + ci) * 256 + t] + tr[(16 + pi) * 256 + t];
        if (r == 3) v += b1[t];
        comb[(size_t)b * 256 + t] = f2b(v);
    }
}

// ---------------- counting-sort scan, phase A: per-block (2048-elem) totals
__global__ __launch_bounds__(256) void scan_block_sums(const int* __restrict__ cnt,
                                                       int* __restrict__ bsum) {
    __shared__ int sm[256];
    int b = blockIdx.x, t = threadIdx.x;
    int base = b * CHUNK + t * 8, s = 0;
#pragma unroll
    for (int j = 0; j < 8; ++j) { int i = base + j; if (i < NB) s += cnt[i]; }
    sm[t] = s; __syncthreads();
    for (int st = 128; st; st >>= 1) { if (t < st) sm[t] += sm[t + st]; __syncthreads(); }
    if (!t) bsum[b] = sm[0];
}

// ---------------- phase B+C merged: inline cross-block base + in-block scan
__global__ __launch_bounds__(256) void scan_write(const int* __restrict__ cnt,
                                                  const int* __restrict__ bsum,
                                                  int* __restrict__ off,
                                                  int* __restrict__ cursor) {
    int b = blockIdx.x, t = threadIdx.x;
    int bbase = 0;                              // wave-uniform 74-iteration prefix
    for (int i = 0; i < b; ++i) bbase += bsum[i];
    if (b == 0 && t == 0) {
        int tot = 0;
        for (int i = 0; i < NBLK; ++i) tot += bsum[i];
        off[NB] = tot;                          // == NE
    }
    int base = b * CHUNK + t * 8;
    int v[8], ts = 0;
#pragma unroll
    for (int j = 0; j < 8; ++j) { int i = base + j; v[j] = (i < NB) ? cnt[i] : 0; ts += v[j]; }
    int lane = t & 63, wv = t >> 6;
    int incl = ts;
    for (int d = 1; d < 64; d <<= 1) {
        int o = __shfl_up(incl, d, 64);
        if (lane >= d) incl += o;
    }
    __shared__ int wsum[4];
    if (lane == 63) wsum[wv] = incl;
    __syncthreads();
    int wbase = 0;
    for (int w = 0; w < wv; ++w) wbase += wsum[w];
    int run = bbase + wbase + incl - ts;
#pragma unroll
    for (int j = 0; j < 8; ++j) {
        int i = base + j;
        if (i < NB) { off[i] = run; cursor[i] = run; }
        run += v[j];
    }
}

// ---------------- bucket-sort edges: stores src AND combo[src]
__global__ __launch_bounds__(256) void scatter_edges(const int* __restrict__ ei,
                                                     const int* __restrict__ et,
                                                     const int* __restrict__ combo,
                                                     int* __restrict__ cursor,
                                                     int* __restrict__ eidx,
                                                     int* __restrict__ ecmb) {
    int e = blockIdx.x * 256 + threadIdx.x;
    if (e >= NE) return;
    int b = ei[NE + e] * NR + et[e];
    int pos = atomicAdd(&cursor[b], 1);
    int s = ei[e];
    eidx[pos] = s;
    ecmb[pos] = combo[s];
}

// ---------------- fused layer 1: 4 waves/block, 1 wave/dst, lane-split 8-deep gather
__global__ __launch_bounds__(256) void l1_fused(const int* __restrict__ off,
                                                const int* __restrict__ ecmb,
                                                const int* __restrict__ combo,
                                                const bf16* __restrict__ comb,
                                                bf16* __restrict__ h1) {
    int wave = threadIdx.x >> 6, lane = threadIdx.x & 63;
    int dst = blockIdx.x * 4 + wave;
    if (dst >= NN) return;
    int half = lane >> 5, li8 = (lane & 31) * 8;
    float acc[8];
    if (half == 0) {   // root slice (b1 pre-folded); only half0's acc is used
        int cmbD = combo[dst];
        short8 rv = *(const short8*)(comb + ((size_t)(3 * NCMB) + cmbD) * 256 + li8);
#pragma unroll
        for (int i = 0; i < 8; ++i) acc[i] = bs2f(rv[i]);
    } else {
#pragma unroll
        for (int i = 0; i < 8; ++i) acc[i] = 0.f;
    }
    for (int r = 0; r < NR; ++r) {
        int lo = off[dst * NR + r], hi = off[dst * NR + r + 1];
        if (hi <= lo) continue;                 // empty bucket contributes 0 (matches ref)
        const bf16* cr = comb + (size_t)r * NCMB * 256;
        float s[8] = {};
        int j = lo;
        for (; j + 8 <= hi; j += 8) {           // 4 rows/half in flight
            int c0 = ecmb[j + half],     c1 = ecmb[j + 2 + half];
            int c2 = ecmb[j + 4 + half], c3 = ecmb[j + 6 + half];
            short8 v0 = *(const short8*)(cr + (size_t)c0 * 256 + li8);
            short8 v1 = *(const short8*)(cr + (size_t)c1 * 256 + li8);
            short8 v2 = *(const short8*)(cr + (size_t)c2 * 256 + li8);
            short8 v3 = *(const short8*)(cr + (size_t)c3 * 256 + li8);
#pragma unroll
            for (int i = 0; i < 8; ++i)
                s[i] += (bs2f(v0[i]) + bs2f(v1[i])) + (bs2f(v2[i]) + bs2f(v3[i]));
        }
        for (; j + 2 <= hi; j += 2) {
            int c0 = ecmb[j + half];
            short8 v0 = *(const short8*)(cr + (size_t)c0 * 256 + li8);
#pragma unroll
            for (int i = 0; i < 8; ++i) s[i] += bs2f(v0[i]);
        }
        if (j < hi && half == 0) {              // odd remainder
            short8 v0 = *(const short8*)(cr + (size_t)ecmb[j] * 256 + li8);
#pragma unroll
            for (int i = 0; i < 8; ++i) s[i] += bs2f(v0[i]);
        }
        float inv = 1.0f / (float)(hi - lo);
#pragma unroll
        for (int i = 0; i < 8; ++i) {
            float tot = s[i] + __shfl_xor(s[i], 32);
            if (half == 0) acc[i] += tot * inv;
        }
    }
    if (half == 0) {
        short8 o;
#pragma unroll
        for (int i = 0; i < 8; ++i) o[i] = f2bs(fmaxf(acc[i], 0.f));
        *(short8*)(h1 + (size_t)dst * 256 + li8) = o;
    }
}

// ---------------- per-relation mean aggregation of h1:
// hagg[dst][r*256+d] = mean_{src in bucket(dst,r)} h1[src][d]   (0 if empty)
__global__ __launch_bounds__(256) void agg_all(const int* __restrict__ off,
                                               const int* __restrict__ eidx,
                                               const bf16* __restrict__ h1,
                                               bf16* __restrict__ hagg) {
    int wave = threadIdx.x >> 6, lane = threadIdx.x & 63;
    int dst = blockIdx.x * 4 + wave;
    if (dst >= NN) return;
    int half = lane >> 5, li8 = (lane & 31) * 8;
    for (int r = 0; r < NR; ++r) {
        int lo = off[dst * NR + r], hi = off[dst * NR + r + 1];
        float s[8] = {};
        int j = lo;
        for (; j + 8 <= hi; j += 8) {           // 4 rows/half in flight
            int e0 = eidx[j + half],     e1 = eidx[j + 2 + half];
            int e2 = eidx[j + 4 + half], e3 = eidx[j + 6 + half];
            short8 v0 = *(const short8*)(h1 + (size_t)e0 * 256 + li8);
            short8 v1 = *(const short8*)(h1 + (size_t)e1 * 256 + li8);
            short8 v2 = *(const short8*)(h1 + (size_t)e2 * 256 + li8);
            short8 v3 = *(const short8*)(h1 + (size_t)e3 * 256 + li8);
#pragma unroll
            for (int i = 0; i < 8; ++i)
                s[i] += (bs2f(v0[i]) + bs2f(v1[i])) + (bs2f(v2[i]) + bs2f(v3[i]));
        }
        for (; j + 2 <= hi; j += 2) {
            int e0 = eidx[j + half];
            short8 v0 = *(const short8*)(h1 + (size_t)e0 * 256 + li8);
#pragma unroll
            for (int i = 0; i < 8; ++i) s[i] += bs2f(v0[i]);
        }
        if (j < hi && half == 0) {
            short8 v0 = *(const short8*)(h1 + (size_t)eidx[j] * 256 + li8);
#pragma unroll
            for (int i = 0; i < 8; ++i) s[i] += bs2f(v0[i]);
        }
        float inv = (hi > lo) ? 1.0f / (float)(hi - lo) : 0.f;
        short8 o;
#pragma unroll
        for (int i = 0; i < 8; ++i) {
            float tot = s[i] + __shfl_xor(s[i], 32);
            o[i] = f2bs(tot * inv);
        }
        if (half == 0)
            *(short8*)(hagg + (size_t)dst * 768 + r * 256 + li8) = o;
    }
}

// ---------------- concat MFMA GEMM v7: v6 ping-pong structure, but block = 32 rows
// x 256 cols (wave w = col-group w). Grid 1563 blocks -> ~6 blocks/CU (2x TLP of
// v6's 782). The 4 waves issue IDENTICAL A addresses -> wave 0 misses, waves 1-3
// hit L1. Wave-autonomous: no __syncthreads anywhere.
__global__ __launch_bounds__(256) void gemm_cat(const bf16* __restrict__ hagg,
                                                const bf16* __restrict__ h1,
                                                const bf16* __restrict__ Wf,
                                                const float* __restrict__ bias,
                                                bf16* __restrict__ h2) {
    __shared__ short lds[4][2][32 * 40];    // per-wave, parity-double-buffered A chunk
    const int t = threadIdx.x;
    const int wave = t >> 6, lane = t & 63;
    const int quad = lane >> 4, l16 = lane & 15;
    const int row0 = blockIdx.x * 32;
    const int colblk = wave;                // 0..3 -> 64-col group
    const int rsub = lane >> 2;        // 0..15: row within 16-row half
    const int ksub = (lane & 3) * 8;   // k-element offset within 32-chunk
    short* A0 = lds[wave][0];
    short* A1 = lds[wave][1];

    const int r0 = min(row0 + rsub, NN - 1);        // clamped (stores guarded)
    const int r1 = min(row0 + 16 + rsub, NN - 1);
    const bf16* gA0 = hagg + (size_t)r0 * 768 + ksub;
    const bf16* gA1 = hagg + (size_t)r1 * 768 + ksub;
    const bf16* gH0 = h1 + (size_t)r0 * 256 + ksub;
    const bf16* gH1 = h1 + (size_t)r1 * 256 + ksub;
    const short8* bbase = (const short8*)Wf + (size_t)colblk * 32 * 4 * 64 + lane;

    auto loadA2 = [&](int k0, short8& a0, short8& a1) {
        if (k0 < 768) { a0 = *(const short8*)(gA0 + k0); a1 = *(const short8*)(gA1 + k0); }
        else          { a0 = *(const short8*)(gH0 + k0 - 768); a1 = *(const short8*)(gH1 + k0 - 768); }
    };
    auto loadB = [&](int chunk, short8* bf4) {
        const short8* bp = bbase + (size_t)chunk * 4 * 64;
#pragma unroll
        for (int ni = 0; ni < 4; ++ni) bf4[ni] = bp[ni * 64];
    };

    floatx4 acc[2][4] = {};
    short8 aE0, aE1, bE[4];     // even-chunk register set
    short8 aO0, aO1, bO[4];     // odd-chunk register set
    loadA2(0, aE0, aE1);  loadB(0, bE);
    loadA2(32, aO0, aO1); loadB(1, bO);

#pragma unroll
    for (int i = 0; i < 32; i += 2) {
        // ---- even chunk i: parity buffer 0, set E
        *(short8*)&A0[rsub * 40 + ksub] = aE0;
        *(short8*)&A0[(16 + rsub) * 40 + ksub] = aE1;
        {
            short8 af0 = *(const short8*)&A0[l16 * 40 + quad * 8];
            short8 af1 = *(const short8*)&A0[(16 + l16) * 40 + quad * 8];
#pragma unroll
            for (int ni = 0; ni < 4; ++ni) {
                acc[0][ni] = __builtin_amdgcn_mfma_f32_16x16x32_bf16(af0, bE[ni], acc[0][ni], 0, 0, 0);
                acc[1][ni] = __builtin_amdgcn_mfma_f32_16x16x32_bf16(af1, bE[ni], acc[1][ni], 0, 0, 0);
            }
        }
        if (i + 2 < 32) { loadA2((i + 2) * 32, aE0, aE1); loadB(i + 2, bE); }
        // ---- odd chunk i+1: parity buffer 1, set O
        *(short8*)&A1[rsub * 40 + ksub] = aO0;
        *(short8*)&A1[(16 + rsub) * 40 + ksub] = aO1;
        {
            short8 af0 = *(const short8*)&A1[l16 * 40 + quad * 8];
            short8 af1 = *(const short8*)&A1[(16 + l16) * 40 + quad * 8];
#pragma unroll
            for (int ni = 0; ni < 4; ++ni) {
                acc[0][ni] = __builtin_amdgcn_mfma_f32_16x16x32_bf16(af0, bO[ni], acc[0][ni], 0, 0, 0);
                acc[1][ni] = __builtin_amdgcn_mfma_f32_16x16x32_bf16(af1, bO[ni], acc[1][ni], 0, 0, 0);
            }
        }
        if (i + 3 < 32) { loadA2((i + 3) * 32, aO0, aO1); loadB(i + 3, bO); }
    }

    // C/D layout: col = lane&15, row = quad*4 + reg   [m89/m91-verified]
#pragma unroll
    for (int mi = 0; mi < 2; ++mi) {
#pragma unroll
        for (int ni = 0; ni < 4; ++ni) {
            int n = colblk * 64 + ni * 16 + l16;
            float bn = bias[n];
#pragma unroll
            for (int ii = 0; ii < 4; ++ii) {
                int gm = row0 + mi * 16 + quad * 4 + ii;
                if (gm < NN) {
                    float v = acc[mi][ni][ii] + bn;
                    h2[(size_t)gm * 256 + n] = f2b(fmaxf(v, 0.f));
                }
            }
        }
    }
}

// ---------------- pooling via run-length reduction (batch is SORTED)
#define PN 64
__global__ __launch_bounds__(256) void pool_rle(const int* __restrict__ batch,
                                                const bf16* __restrict__ H,
                                                float* __restrict__ pool,
                                                float* __restrict__ gcnt) {
    int t = threadIdx.x;               // feature dim
    int n0 = blockIdx.x * PN;
    int nend = n0 + PN; if (nend > NN) nend = NN;
    int curg = batch[n0];
    float acc = 0.f, cnt = 0.f;
    for (int n = n0; n < nend; ++n) {
        int g = batch[n];              // wave-uniform
        if (g != curg) {
            atomicAdd(&pool[(size_t)curg * 256 + t], acc);
            if (t == 0) atomicAdd(&gcnt[curg], cnt);
            acc = 0.f; cnt = 0.f; curg = g;
        }
        acc += b2f(H[(size_t)n * 256 + t]);
        cnt += 1.f;
    }
    atomicAdd(&pool[(size_t)curg * 256 + t], acc);
    if (t == 0) atomicAdd(&gcnt[curg], cnt);
}

// ---------------- head: out[g][c] = (pool[g]/cnt[g]) @ lin_w + lin_b  (f32 out)
__global__ __launch_bounds__(256) void final_head(const float* __restrict__ pool,
                                                  const float* __restrict__ gcnt,
                                                  const float* __restrict__ lin_w,
                                                  const float* __restrict__ lin_b,
                                                  float* __restrict__ out) {
    __shared__ float sm[256];
    int g = blockIdx.x, t = threadIdx.x;
    float inv = 1.0f / fmaxf(gcnt[g], 1.0f);
    sm[t] = pool[(size_t)g * 256 + t] * inv;
    __syncthreads();
    if (t < NCLS) {
        float s = lin_b[t];
        for (int d = 0; d < 256; ++d) s += sm[d] * lin_w[d * NCLS + t];
        out[g * NCLS + t] = s;
    }
}

extern "C" void kernel_launch(void* const* d_in, const int* in_sizes, int n_in,
                              void* d_out, int out_size, void* d_ws, size_t ws_size,
                              hipStream_t stream) {
    const int*   s_idx = (const int*)d_in[0];
    const int*   c_idx = (const int*)d_in[1];
    const int*   p_idx = (const int*)d_in[2];
    const int*   ei    = (const int*)d_in[3];   // (2, NE)
    const int*   et    = (const int*)d_in[4];
    const int*   batch = (const int*)d_in[5];
    const float* se    = (const float*)d_in[6];
    const float* ce    = (const float*)d_in[7];
    const float* pe    = (const float*)d_in[8];
    const float* W1    = (const float*)d_in[9];   // (3, 384, 256)
    const float* root1 = (const float*)d_in[10];  // (384, 256)
    const float* b1    = (const float*)d_in[11];
    const float* W2    = (const float*)d_in[12];  // (3, 256, 256)
    const float* root2 = (const float*)d_in[13];  // (256, 256)
    const float* b2    = (const float*)d_in[14];
    const float* lin_w = (const float*)d_in[15];
    const float* lin_b = (const float*)d_in[16];
    float* out = (float*)d_out;

    // ---- workspace carve-up (~175 MB; ws_size >= 190 MB confirmed in round 6)
    char* w = (char*)d_ws;
    size_t o = 0;
    auto alloc = [&](size_t bytes) -> void* {
        o = (o + 15) & ~(size_t)15;
        void* ptr = w + o;
        o += bytes;
        return ptr;
    };
    bf16*  hagg   = (bf16*) alloc((size_t)NN * 768 * 2);   // 76.8 MB
    bf16*  h1     = (bf16*) alloc((size_t)NN * 256 * 2);
    bf16*  h2     = (bf16*) alloc((size_t)NN * 256 * 2);
    bf16*  comb   = (bf16*) alloc((size_t)4 * NCMB * 256 * 2);
    int*   combo  = (int*)  alloc((size_t)NN * 4);
    int*   eidx   = (int*)  alloc((size_t)NE * 4);
    int*   ecmb   = (int*)  alloc((size_t)NE * 4);
    int*   cnt    = (int*)  alloc((size_t)NB * 4);
    int*   off    = (int*)  alloc((size_t)(NB + 1) * 4);
    int*   cursor = (int*)  alloc((size_t)NB * 4);
    int*   bsum   = (int*)  alloc((size_t)NBLK * 4);
    float* tab    = (float*)alloc((size_t)4 * 144 * 256 * 4);
    bf16*  Wf     = (bf16*) alloc((size_t)256 * 1024 * 2);
    float* pool   = (float*)alloc((size_t)NG * 256 * 4);   // pool + gcnt contiguous
    float* gcnt   = (float*)alloc((size_t)NG * 4);
    (void)ws_size;

    // ---- 1. all independent prep (combo ids, zeros, layer-1 tab GEMM, Wf shuffle)
    prep1<<<P1_TOTAL, 256, 0, stream>>>(s_idx, c_idx, p_idx, se, ce, pe,
                                        W1, root1, W2, root2,
                                        combo, (unsigned*)cnt, (unsigned*)pool, tab, Wf);
    // ---- 2. edge counts + combo-table build
    prep2<<<P2_TOTAL, 256, 0, stream>>>(ei, et, cnt, tab, b1, comb);
    // ---- 3-5. CSR: scan + scatter
    scan_block_sums<<<NBLK, 256, 0, stream>>>(cnt, bsum);
    scan_write<<<NBLK, 256, 0, stream>>>(cnt, bsum, off, cursor);
    scatter_edges<<<(NE + 255) / 256, 256, 0, stream>>>(ei, et, combo, cursor, eidx, ecmb);
    // ---- 6. layer 1: fully fused combo-table gather
    l1_fused<<<(NN + 3) / 4, 256, 0, stream>>>(off, ecmb, combo, comb, h1);
    // ---- 7-8. layer 2: aggregate-first, then one wave-autonomous concat GEMM
    agg_all<<<(NN + 3) / 4, 256, 0, stream>>>(off, eidx, h1, hagg);
    gemm_cat<<<(NN + 31) / 32, 256, 0, stream>>>(hagg, h1, Wf, b2, h2);
    // ---- 9-10. pool + head
    pool_rle<<<(NN + PN - 1) / PN, 256, 0, stream>>>(batch, h2, pool, gcnt);
    final_head<<<NG, 256, 0, stream>>>(pool, gcnt, lin_w, lin_b, out);
}